// Round 3
// baseline (419.818 us; speedup 1.0000x reference)
//
#include <hip/hip_runtime.h>
#include <math.h>

#define B_ 32
#define HW_ 4096
#define N_ 16
#define C_ 128
#define F_ 512
#define ITERS_ 3
#define EPS_LN 1e-5f
#define EPS_ATTN 1e-5f

typedef __attribute__((ext_vector_type(8))) short short8;
typedef __attribute__((ext_vector_type(4))) float f32x4;

static __device__ __forceinline__ unsigned short f2b(float f) {
    union { float f; unsigned u; } v; v.f = f;
    unsigned r = v.u + 0x7fffu + ((v.u >> 16) & 1u);
    return (unsigned short)(r >> 16);
}
static __device__ __forceinline__ float blo(unsigned u) {
    union { unsigned u; float f; } v; v.u = u << 16; return v.f;
}
static __device__ __forceinline__ float bhi(unsigned u) {
    union { unsigned u; float f; } v; v.u = u & 0xffff0000u; return v.f;
}

// ---------------------------------------------------------------------------
// One-time prep.
// Blocks 0..31:    flat fp32->bf16 of Wk, Wv (for k_kvproj MFMA staging).
// Blocks 32..255:  transpose-packed bf16 of wih/whh/w1/w2 for k_tail:
//                  packed[(g*R + o)] (uint2) = W[o][4g .. 4g+3], so that for
//                  fixed input-group g the 64 lanes (outputs o=lane+64k) read
//                  one contiguous 512B segment -> fully coalesced GEMV loads.
// Blocks 256..287: qn_0 = (LN(query)*g+b) @ Wq^T * scale.
// ---------------------------------------------------------------------------
__global__ __launch_bounds__(256) void k_prep(
    const float* __restrict__ Wk, const float* __restrict__ Wv,
    const float* __restrict__ wih, const float* __restrict__ whh,
    const float* __restrict__ w1, const float* __restrict__ w2,
    unsigned short* __restrict__ Wk_bf, unsigned short* __restrict__ Wv_bf,
    unsigned short* __restrict__ wihT, unsigned short* __restrict__ whhT,
    unsigned short* __restrict__ w1T, unsigned short* __restrict__ w2T,
    const float* __restrict__ query, const float* __restrict__ lnqg,
    const float* __restrict__ lnqb, const float* __restrict__ Wq,
    unsigned short* __restrict__ qn_g)
{
    __shared__ __align__(16) float xq[16 * 128];
    int tid = threadIdx.x;
    int blk = blockIdx.x;
    if (blk < 32) {
        int t = blk * 256 + tid;
        const float* src; unsigned short* dst; int off;
        if (t < 4096) { src = Wk; dst = Wk_bf; off = t; }
        else          { src = Wv; dst = Wv_bf; off = t - 4096; }
        float4 a = ((const float4*)src)[off];
        uint2 p;
        p.x = (unsigned)f2b(a.x) | ((unsigned)f2b(a.y) << 16);
        p.y = (unsigned)f2b(a.z) | ((unsigned)f2b(a.w) << 16);
        *(uint2*)(dst + off * 4) = p;
        return;
    }
    if (blk < 256) {
        // transpose-pack: read W[o][4g..4g+3] (float4), write packed[id] (uint2)
        const float* src; unsigned short* dst; int o, g, id, Cin;
        if (blk < 80) {         // wih: R=384, Cin=128, 12288 ids
            id = (blk - 32) * 256 + tid;
            g = id / 384; o = id - g * 384;
            src = wih; dst = wihT; Cin = 128;
        } else if (blk < 128) { // whh: R=384
            id = (blk - 80) * 256 + tid;
            g = id / 384; o = id - g * 384;
            src = whh; dst = whhT; Cin = 128;
        } else if (blk < 192) { // w1: R=512, Cin=128, 16384 ids
            id = (blk - 128) * 256 + tid;
            g = id >> 9; o = id & 511;
            src = w1; dst = w1T; Cin = 128;
        } else {                // w2: R=128, Cin=512, 16384 ids
            id = (blk - 192) * 256 + tid;
            g = id >> 7; o = id & 127;
            src = w2; dst = w2T; Cin = 512;
        }
        float4 a = *(const float4*)(src + o * Cin + g * 4);
        uint2 p;
        p.x = (unsigned)f2b(a.x) | ((unsigned)f2b(a.y) << 16);
        p.y = (unsigned)f2b(a.z) | ((unsigned)f2b(a.w) << 16);
        *(uint2*)(dst + id * 4) = p;
        return;
    }
    int b = blk - 256;
    int n = tid >> 4, part = tid & 15;
    int row = b * 16 + n;
    const float4* x4 = (const float4*)(query + row * 128 + part * 8);
    float4 x0 = x4[0], x1 = x4[1];
    float s = x0.x + x0.y + x0.z + x0.w + x1.x + x1.y + x1.z + x1.w;
    float ss = x0.x * x0.x + x0.y * x0.y + x0.z * x0.z + x0.w * x0.w +
               x1.x * x1.x + x1.y * x1.y + x1.z * x1.z + x1.w * x1.w;
    s += __shfl_xor(s, 1); s += __shfl_xor(s, 2); s += __shfl_xor(s, 4); s += __shfl_xor(s, 8);
    ss += __shfl_xor(ss, 1); ss += __shfl_xor(ss, 2); ss += __shfl_xor(ss, 4); ss += __shfl_xor(ss, 8);
    float mean = s * (1.f / 128.f);
    float var = ss * (1.f / 128.f) - mean * mean;
    float rstd = rsqrtf(var + EPS_LN);
    const float4* g4 = (const float4*)(lnqg + part * 8);
    const float4* b4 = (const float4*)(lnqb + part * 8);
    float4 g0 = g4[0], g1 = g4[1], bb0 = b4[0], bb1 = b4[1];
    float4 o0, o1;
    o0.x = (x0.x - mean) * rstd * g0.x + bb0.x;
    o0.y = (x0.y - mean) * rstd * g0.y + bb0.y;
    o0.z = (x0.z - mean) * rstd * g0.z + bb0.z;
    o0.w = (x0.w - mean) * rstd * g0.w + bb0.w;
    o1.x = (x1.x - mean) * rstd * g1.x + bb1.x;
    o1.y = (x1.y - mean) * rstd * g1.y + bb1.y;
    o1.z = (x1.z - mean) * rstd * g1.z + bb1.z;
    o1.w = (x1.w - mean) * rstd * g1.w + bb1.w;
    float4* xrow = (float4*)&xq[n * 128];
    xrow[part * 2] = o0;
    xrow[part * 2 + 1] = o1;
    __syncthreads();
    float o[8] = {0.f, 0.f, 0.f, 0.f, 0.f, 0.f, 0.f, 0.f};
    const float4* xv4 = (const float4*)&xq[n * 128];
#pragma unroll 4
    for (int j = 0; j < 32; j++) {
        float4 xv = xv4[j];
#pragma unroll
        for (int i = 0; i < 8; i++) {
            float4 w = ((const float4*)(Wq + (part * 8 + i) * 128))[j];
            o[i] += w.x * xv.x + w.y * xv.y + w.z * xv.z + w.w * xv.w;
        }
    }
    const float scale = 0.08838834764831845f;
#pragma unroll
    for (int i = 0; i < 8; i++)
        qn_g[row * 128 + part * 8 + i] = f2b(o[i] * scale);
}

// ---------------------------------------------------------------------------
// Kernel 1 (round-0 proven version, 54.6us): kv = LN(inp); K -> [b][hw][c];
// V -> [b][c][hw]. 64 rows/block. In-register LN. XOR-swizzled W_lds.
// (Global-W variant regressed to 94.5us; LDS staging is the latency fix.)
// ---------------------------------------------------------------------------
__global__ __launch_bounds__(256) void k_kvproj(
    const float* __restrict__ inp, const float* __restrict__ lng,
    const float* __restrict__ lnb, const unsigned short* __restrict__ Wk_bf,
    const unsigned short* __restrict__ Wv_bf, unsigned short* __restrict__ Kbf,
    unsigned short* __restrict__ Vt)
{
    __shared__ __align__(16) unsigned short W_lds[128 * 128];  // 32 KB
    __shared__ __align__(16) unsigned short T_lds[8960];       // 17.9 KB
    const int tid = threadIdx.x;
    const int wave = tid >> 6, lane = tid & 63;
    const int l15 = lane & 15, q4 = lane >> 4;
    const int kof = q4 * 8;
    const int tile0 = blockIdx.x * 64;
    const int b = tile0 >> 12;
    const int hwbase = tile0 & (HW_ - 1);

    const int srow = tid >> 1, shalf = tid & 1;
    const int sswz = srow & 7;

    // ---- in-register LN ----
    float x[4][8];
    {
        const float* rowp = inp + (tile0 + (wave << 4) + l15) * C_;
        float s = 0.f, ss = 0.f;
#pragma unroll
        for (int ks = 0; ks < 4; ks++) {
#pragma unroll
            for (int h = 0; h < 2; h++) {
                float4 v = *(const float4*)(rowp + ks * 32 + kof + h * 4);
                x[ks][h * 4 + 0] = v.x; x[ks][h * 4 + 1] = v.y;
                x[ks][h * 4 + 2] = v.z; x[ks][h * 4 + 3] = v.w;
                s += v.x + v.y + v.z + v.w;
                ss += v.x * v.x + v.y * v.y + v.z * v.z + v.w * v.w;
            }
        }
        s += __shfl_xor(s, 16);  s += __shfl_xor(s, 32);
        ss += __shfl_xor(ss, 16); ss += __shfl_xor(ss, 32);
        float mean = s * (1.f / 128.f);
        float var = ss * (1.f / 128.f) - mean * mean;
        float rstd = rsqrtf(var + EPS_LN);
#pragma unroll
        for (int ks = 0; ks < 4; ks++) {
#pragma unroll
            for (int h = 0; h < 2; h++) {
                float4 g = *(const float4*)(lng + ks * 32 + kof + h * 4);
                float4 bb = *(const float4*)(lnb + ks * 32 + kof + h * 4);
                x[ks][h * 4 + 0] = (x[ks][h * 4 + 0] - mean) * rstd * g.x + bb.x;
                x[ks][h * 4 + 1] = (x[ks][h * 4 + 1] - mean) * rstd * g.y + bb.y;
                x[ks][h * 4 + 2] = (x[ks][h * 4 + 2] - mean) * rstd * g.z + bb.z;
                x[ks][h * 4 + 3] = (x[ks][h * 4 + 3] - mean) * rstd * g.w + bb.w;
            }
        }
    }
    short8 af[4];
#pragma unroll
    for (int ks = 0; ks < 4; ks++) {
        union { short8 s8; unsigned u[4]; } p;
#pragma unroll
        for (int j = 0; j < 4; j++)
            p.u[j] = (unsigned)f2b(x[ks][2 * j]) | ((unsigned)f2b(x[ks][2 * j + 1]) << 16);
        af[ks] = p.s8;
    }

    // ---- stage Wk (swizzled) ----
    {
        const uint4* gW = (const uint4*)Wk_bf;
#pragma unroll
        for (int j = 0; j < 8; j++) {
            int c = shalf * 8 + j;
            uint4 w = gW[srow * 16 + c];
            *(uint4*)&W_lds[srow * 128 + (c ^ sswz) * 8] = w;
        }
    }
    __syncthreads();

    f32x4 acc[8];
    // ---- K phase ----
#pragma unroll
    for (int nt = 0; nt < 8; nt++) {
        acc[nt] = (f32x4){0.f, 0.f, 0.f, 0.f};
#pragma unroll
        for (int ks = 0; ks < 4; ks++) {
            short8 bf = *(const short8*)&W_lds[(nt * 16 + l15) * 128 + ((ks * 4 + q4) ^ (l15 & 7)) * 8];
            acc[nt] = __builtin_amdgcn_mfma_f32_16x16x32_bf16(af[ks], bf, acc[nt], 0, 0, 0);
        }
    }
    // K acc -> T [m][132]
#pragma unroll
    for (int nt = 0; nt < 8; nt++) {
        int c = nt * 16 + l15;
#pragma unroll
        for (int i = 0; i < 4; i++)
            T_lds[((wave << 4) + (q4 << 2) + i) * 132 + c] = f2b(acc[nt][i]);
    }
    __syncthreads();
    // K coalesced stores + stage Wv
    {
        int row = tid >> 2, part = tid & 3;
        uint4* dst = (uint4*)&Kbf[(b * HW_ + hwbase + row) * C_ + part * 32];
#pragma unroll
        for (int j = 0; j < 4; j++)
            dst[j] = *(const uint4*)&T_lds[row * 132 + part * 32 + j * 8];
    }
    {
        const uint4* gW = (const uint4*)Wv_bf;
#pragma unroll
        for (int j = 0; j < 8; j++) {
            int c = shalf * 8 + j;
            uint4 w = gW[srow * 16 + c];
            *(uint4*)&W_lds[srow * 128 + (c ^ sswz) * 8] = w;
        }
    }
    __syncthreads();
    // ---- V phase ----
#pragma unroll
    for (int nt = 0; nt < 8; nt++) {
        acc[nt] = (f32x4){0.f, 0.f, 0.f, 0.f};
#pragma unroll
        for (int ks = 0; ks < 4; ks++) {
            short8 bf = *(const short8*)&W_lds[(nt * 16 + l15) * 128 + ((ks * 4 + q4) ^ (l15 & 7)) * 8];
            acc[nt] = __builtin_amdgcn_mfma_f32_16x16x32_bf16(af[ks], bf, acc[nt], 0, 0, 0);
        }
    }
    __syncthreads();
    // V acc -> T2 transposed [c][70]
#pragma unroll
    for (int nt = 0; nt < 8; nt++) {
        int c = nt * 16 + l15;
#pragma unroll
        for (int i = 0; i < 4; i++)
            T_lds[c * 70 + (wave << 4) + (q4 << 2) + i] = f2b(acc[nt][i]);
    }
    __syncthreads();
    // V stores: vectorized from T2
    {
        int c = tid >> 1, half = tid & 1;
        uint4* dst = (uint4*)&Vt[(b * C_ + c) * HW_ + hwbase + half * 32];
#pragma unroll
        for (int j = 0; j < 4; j++)
            dst[j] = *(const uint4*)&T_lds[c * 70 + half * 32 + j * 8];
    }
}

// ---------------------------------------------------------------------------
// Kernel 2 (per iter): 256-thread blocks (4 waves), grid (32, B).
// Each wave: 32 hw -> 2 score tiles + column softmax + PV (1 k-chunk).
// ---------------------------------------------------------------------------
__global__ __launch_bounds__(256) void k_attn(
    const unsigned short* __restrict__ qn_g, const unsigned short* __restrict__ Kbf,
    const unsigned short* __restrict__ Vt, float* __restrict__ Upart,
    float* __restrict__ rspart, float* __restrict__ a0_out, int last)
{
    __shared__ __align__(16) float Ul[4][16 * 132];          // 33.8 KB
    __shared__ __align__(16) unsigned short Pb[4][16 * 40];  // 5.1 KB
    __shared__ float rsw[4][16];
    const int b = blockIdx.y, chunk = blockIdx.x;
    const int tid = threadIdx.x;
    const int wave = tid >> 6, lane = tid & 63;
    const int l15 = lane & 15, q4 = lane >> 4;
    const int kof = q4 * 8;
    const int hwb = chunk * 128 + wave * 32;

    short8 aq[4];
#pragma unroll
    for (int ks = 0; ks < 4; ks++)
        aq[ks] = *(const short8*)&qn_g[(b * 16 + l15) * 128 + ks * 32 + kof];
    // preload PV A-fragments early (independent of score chain)
    short8 av[8];
#pragma unroll
    for (int ct = 0; ct < 8; ct++)
        av[ct] = *(const short8*)&Vt[(b * C_ + ct * 16 + l15) * HW_ + hwb + kof];

    unsigned short* Pw = &Pb[wave][0];
    float rs[4] = {0.f, 0.f, 0.f, 0.f};
#pragma unroll
    for (int s = 0; s < 2; s++) {
        int hwt = hwb + s * 16;
        f32x4 sa = {0.f, 0.f, 0.f, 0.f};
#pragma unroll
        for (int ks = 0; ks < 4; ks++) {
            short8 bk = *(const short8*)&Kbf[(b * HW_ + hwt + l15) * C_ + ks * 32 + kof];
            sa = __builtin_amdgcn_mfma_f32_16x16x32_bf16(aq[ks], bk, sa, 0, 0, 0);
        }
        float mx = fmaxf(fmaxf(sa[0], sa[1]), fmaxf(sa[2], sa[3]));
        mx = fmaxf(mx, __shfl_xor(mx, 16));
        mx = fmaxf(mx, __shfl_xor(mx, 32));
        float e[4]; float ssum = 0.f;
#pragma unroll
        for (int i = 0; i < 4; i++) { e[i] = __expf(sa[i] - mx); ssum += e[i]; }
        ssum += __shfl_xor(ssum, 16);
        ssum += __shfl_xor(ssum, 32);
        float inv = 1.f / ssum;
#pragma unroll
        for (int i = 0; i < 4; i++) {
            float a0v = e[i] * inv;
            rs[i] += a0v;
            if (last) a0_out[(b * 16 + q4 * 4 + i) * HW_ + hwt + l15] = a0v;
            Pw[(q4 * 4 + i) * 40 + s * 16 + l15] = f2b(a0v);
        }
    }
    // rowsum (sum over this wave's 32 hw)
#pragma unroll
    for (int i = 0; i < 4; i++) {
        rs[i] += __shfl_xor(rs[i], 1);
        rs[i] += __shfl_xor(rs[i], 2);
        rs[i] += __shfl_xor(rs[i], 4);
        rs[i] += __shfl_xor(rs[i], 8);
    }
    if (l15 == 0) {
#pragma unroll
        for (int i = 0; i < 4; i++) rsw[wave][q4 * 4 + i] = rs[i];
    }
    // PV: same-wave P read (compiler inserts lgkmcnt; P is wave-private)
    short8 bp = *(const short8*)&Pw[l15 * 40 + kof];
#pragma unroll
    for (int ct = 0; ct < 8; ct++) {
        f32x4 ua = __builtin_amdgcn_mfma_f32_16x16x32_bf16(av[ct], bp, (f32x4){0.f, 0.f, 0.f, 0.f}, 0, 0, 0);
        // lane holds q = l15, c = ct*16 + q4*4 + i (i contiguous) -> float4 store
        *(f32x4*)&Ul[wave][l15 * 132 + ct * 16 + (q4 << 2)] = ua;
    }
    __syncthreads();
    // export: Upart layout [q*128 + c], fully coalesced
    {
        float* up = Upart + (b * 32 + chunk) * 2048;
#pragma unroll
        for (int k = 0; k < 8; k++) {
            int idx = tid + k * 256;          // idx = q*128 + c
            int q = idx >> 7, c = idx & 127;
            up[idx] = Ul[0][q * 132 + c] + Ul[1][q * 132 + c] +
                      Ul[2][q * 132 + c] + Ul[3][q * 132 + c];
        }
        if (tid < 16)
            rspart[(b * 32 + chunk) * 16 + tid] =
                rsw[0][tid] + rsw[1][tid] + rsw[2][tid] + rsw[3][tid];
    }
}

// ---------------------------------------------------------------------------
// Kernel 3 v3 (per iter): one row per wave, 64-thread blocks, zero barriers.
// Weights are transpose-packed (k_prep): for input-group g, lane loads
// packed[g*R + lane + 64k] (uint2 = 4 bf16) -> 64 lanes read one contiguous
// 512B segment = fully coalesced (v2's row-per-lane layout was a 64-line
// scatter per load instruction -> 65us latency disaster).
// Activations broadcast from wave-private LDS (same-addr read = free).
// ---------------------------------------------------------------------------
__global__ __launch_bounds__(64) void k_tail(
    const float* __restrict__ Upart, const float* __restrict__ rspart,
    const float* __restrict__ hsrc, float* __restrict__ q_buf,
    const unsigned short* __restrict__ wihT, const unsigned short* __restrict__ whhT,
    const float* __restrict__ bih, const float* __restrict__ bhh,
    const float* __restrict__ ln2g, const float* __restrict__ ln2b,
    const unsigned short* __restrict__ w1T, const float* __restrict__ b1,
    const unsigned short* __restrict__ w2T, const float* __restrict__ b2,
    const float* __restrict__ lnqg, const float* __restrict__ lnqb,
    const float* __restrict__ Wq, unsigned short* __restrict__ qn_g,
    float* __restrict__ out_q, int last)
{
    __shared__ __align__(16) float u_l[128];
    __shared__ __align__(16) float h_l[128];
    __shared__ __align__(16) float z_l[128];
    __shared__ __align__(16) float h1_l[512];
    const int lane = threadIdx.x;
    const int row = blockIdx.x;
    const int b = row >> 4, q = row & 15;

    // ---- u = (sum_ch Upart) / (sum_ch rspart + eps); h load ----
    {
        float2 us = {0.f, 0.f};
        const float* up = Upart + (b * 32) * 2048 + q * 128 + lane * 2;
#pragma unroll 8
        for (int ch = 0; ch < 32; ch++) {
            float2 v = *(const float2*)(up + ch * 2048);
            us.x += v.x; us.y += v.y;
        }
        float rv = (lane < 32) ? rspart[(b * 32 + lane) * 16 + q] : 0.f;
#pragma unroll
        for (int off = 1; off < 64; off <<= 1) rv += __shfl_xor(rv, off);
        float inv = 1.f / (rv + EPS_ATTN);
        *(float2*)&u_l[lane * 2] = (float2){us.x * inv, us.y * inv};
        float2 hv = *(const float2*)(hsrc + row * 128 + lane * 2);
        *(float2*)&h_l[lane * 2] = hv;
    }

    // ---- GRU gates: 12 outputs/lane (o = lane + 64k), coalesced packed W ----
    float acc[12];
#pragma unroll
    for (int k = 0; k < 12; k++) acc[k] = 0.f;
    {
        const uint2* wi2 = (const uint2*)wihT;
        const uint2* wh2 = (const uint2*)whhT;
#pragma unroll 2
        for (int g = 0; g < 32; g++) {
            float4 uv = *(const float4*)&u_l[g * 4];   // broadcast
            float4 hv = *(const float4*)&h_l[g * 4];   // broadcast
#pragma unroll
            for (int k = 0; k < 6; k++) {
                uint2 w = wi2[g * 384 + lane + 64 * k];
                acc[k] += blo(w.x) * uv.x + bhi(w.x) * uv.y
                        + blo(w.y) * uv.z + bhi(w.y) * uv.w;
            }
#pragma unroll
            for (int k = 0; k < 6; k++) {
                uint2 w = wh2[g * 384 + lane + 64 * k];
                acc[6 + k] += blo(w.x) * hv.x + bhi(w.x) * hv.y
                            + blo(w.y) * hv.z + bhi(w.y) * hv.w;
            }
        }
#pragma unroll
        for (int k = 0; k < 6; k++) acc[k] += bih[lane + 64 * k];
#pragma unroll
        for (int k = 6; k < 12; k++) acc[k] += bhh[lane + 64 * (k - 6)];
    }

    // ---- GRU elementwise (channels c = lane and lane+64, all in-lane) ----
    float y0, y1;
    {
        float h0 = h_l[lane], h64 = h_l[lane + 64];
        float r0 = 1.f / (1.f + expf(-(acc[0] + acc[6])));
        float z0 = 1.f / (1.f + expf(-(acc[2] + acc[8])));
        float n0 = tanhf(acc[4] + r0 * acc[10]);
        y0 = (1.f - z0) * n0 + z0 * h0;
        float r1 = 1.f / (1.f + expf(-(acc[1] + acc[7])));
        float z1 = 1.f / (1.f + expf(-(acc[3] + acc[9])));
        float n1 = tanhf(acc[5] + r1 * acc[11]);
        y1 = (1.f - z1) * n1 + z1 * h64;
    }

    // ---- LN2 ----
    {
        float s = y0 + y1, ss = y0 * y0 + y1 * y1;
#pragma unroll
        for (int off = 1; off < 64; off <<= 1) {
            s += __shfl_xor(s, off);
            ss += __shfl_xor(ss, off);
        }
        float mean = s * (1.f / 128.f);
        float var = ss * (1.f / 128.f) - mean * mean;
        float rstd = rsqrtf(var + EPS_LN);
        z_l[lane]      = (y0 - mean) * rstd * ln2g[lane]      + ln2b[lane];
        z_l[lane + 64] = (y1 - mean) * rstd * ln2g[lane + 64] + ln2b[lane + 64];
    }

    // ---- FFN1: 8 outputs/lane (f = lane + 64k), coalesced packed w1 ----
    {
        float fa[8];
#pragma unroll
        for (int k = 0; k < 8; k++) fa[k] = 0.f;
        const uint2* w12 = (const uint2*)w1T;
#pragma unroll 2
        for (int g = 0; g < 32; g++) {
            float4 zv = *(const float4*)&z_l[g * 4];   // broadcast
#pragma unroll
            for (int k = 0; k < 8; k++) {
                uint2 w = w12[g * 512 + lane + 64 * k];
                fa[k] += blo(w.x) * zv.x + bhi(w.x) * zv.y
                       + blo(w.y) * zv.z + bhi(w.y) * zv.w;
            }
        }
#pragma unroll
        for (int k = 0; k < 8; k++)
            h1_l[lane + 64 * k] = fmaxf(fa[k] + b1[lane + 64 * k], 0.f);
    }

    // ---- FFN2: 2 outputs/lane (c = lane, lane+64), coalesced packed w2 ----
    float f2a = 0.f, f2c = 0.f;
    {
        const uint2* w22 = (const uint2*)w2T;   // [g*128 + c], g over F/4=128
#pragma unroll 4
        for (int g = 0; g < 128; g++) {
            float4 hv = *(const float4*)&h1_l[g * 4];  // broadcast
            uint2 wa = w22[g * 128 + lane];
            uint2 wc = w22[g * 128 + lane + 64];
            f2a += blo(wa.x) * hv.x + bhi(wa.x) * hv.y
                 + blo(wa.y) * hv.z + bhi(wa.y) * hv.w;
            f2c += blo(wc.x) * hv.x + bhi(wc.x) * hv.y
                 + blo(wc.y) * hv.z + bhi(wc.y) * hv.w;
        }
    }
    float qn0 = y0 + f2a + b2[lane];
    float qn1 = y1 + f2c + b2[lane + 64];
    q_buf[row * 128 + lane]      = qn0;
    q_buf[row * 128 + lane + 64] = qn1;
    if (last) {
        out_q[row * 128 + lane]      = qn0;
        out_q[row * 128 + lane + 64] = qn1;
        return;
    }

    // ---- qn_next = LN(q_new) @ Wq^T * scale (fp32 Wq, unpacked) ----
    {
        float s = qn0 + qn1, ss = qn0 * qn0 + qn1 * qn1;
#pragma unroll
        for (int off = 1; off < 64; off <<= 1) {
            s += __shfl_xor(s, off);
            ss += __shfl_xor(ss, off);
        }
        float mean = s * (1.f / 128.f);
        float var = ss * (1.f / 128.f) - mean * mean;
        float rstd = rsqrtf(var + EPS_LN);
        z_l[lane]      = (qn0 - mean) * rstd * lnqg[lane]      + lnqb[lane];
        z_l[lane + 64] = (qn1 - mean) * rstd * lnqg[lane + 64] + lnqb[lane + 64];
    }
    {
        const float4* wqa = (const float4*)(Wq + lane * 128);
        const float4* wqc = (const float4*)(Wq + (lane + 64) * 128);
        float qa = 0.f, qc = 0.f;
#pragma unroll 4
        for (int j = 0; j < 32; j++) {
            float4 zf = *(const float4*)&z_l[j * 4];
            float4 wa = wqa[j], wc = wqc[j];
            qa += wa.x * zf.x + wa.y * zf.y + wa.z * zf.z + wa.w * zf.w;
            qc += wc.x * zf.x + wc.y * zf.y + wc.z * zf.z + wc.w * zf.w;
        }
        const float scale = 0.08838834764831845f;
        qn_g[row * 128 + lane]      = f2b(qa * scale);
        qn_g[row * 128 + lane + 64] = f2b(qc * scale);
    }
}

// ---------------------------------------------------------------------------
extern "C" void kernel_launch(void* const* d_in, const int* in_sizes, int n_in,
                              void* d_out, int out_size, void* d_ws, size_t ws_size,
                              hipStream_t stream) {
    const float* inp     = (const float*)d_in[0];
    const float* query   = (const float*)d_in[1];
    const float* ln_kv_g = (const float*)d_in[2];
    const float* ln_kv_b = (const float*)d_in[3];
    const float* Wk      = (const float*)d_in[4];
    const float* Wv      = (const float*)d_in[5];
    const float* ln_q_g  = (const float*)d_in[6];
    const float* ln_q_b  = (const float*)d_in[7];
    const float* Wq      = (const float*)d_in[8];
    const float* gru_wih = (const float*)d_in[9];
    const float* gru_whh = (const float*)d_in[10];
    const float* gru_bih = (const float*)d_in[11];
    const float* gru_bhh = (const float*)d_in[12];
    const float* ln2_g   = (const float*)d_in[13];
    const float* ln2_b   = (const float*)d_in[14];
    const float* ffn_w1  = (const float*)d_in[15];
    const float* ffn_b1  = (const float*)d_in[16];
    const float* ffn_w2  = (const float*)d_in[17];
    const float* ffn_b2  = (const float*)d_in[18];

    char* ws = (char*)d_ws;
    unsigned short* Kbf    = (unsigned short*)ws;                  // 33554432
    unsigned short* Vt     = (unsigned short*)(ws + 33554432);     // 33554432
    float* q_buf           = (float*)(ws + 67108864);              // 262144
    float* Upart           = (float*)(ws + 67371008);              // 8388608
    float* rspart          = (float*)(ws + 75759616);              // 65536
    unsigned short* qn_g   = (unsigned short*)(ws + 75825152);     // 131072
    unsigned short* Wk_bf  = (unsigned short*)(ws + 75956224);     // 32768
    unsigned short* Wv_bf  = (unsigned short*)(ws + 75988992);     // 32768
    unsigned short* wihT   = (unsigned short*)(ws + 76021760);     // 98304
    unsigned short* whhT   = (unsigned short*)(ws + 76120064);     // 98304
    unsigned short* w1T    = (unsigned short*)(ws + 76218368);     // 131072
    unsigned short* w2T    = (unsigned short*)(ws + 76349440);     // 131072

    float* out_q  = (float*)d_out;
    float* out_a0 = out_q + B_ * N_ * C_;

    k_prep<<<dim3(288), dim3(256), 0, stream>>>(
        Wk, Wv, gru_wih, gru_whh, ffn_w1, ffn_w2,
        Wk_bf, Wv_bf, wihT, whhT, w1T, w2T,
        query, ln_q_g, ln_q_b, Wq, qn_g);
    k_kvproj<<<dim3((B_ * HW_) / 64), dim3(256), 0, stream>>>(
        inp, ln_kv_g, ln_kv_b, Wk_bf, Wv_bf, Kbf, Vt);

    for (int it = 0; it < ITERS_; it++) {
        int last = (it == ITERS_ - 1) ? 1 : 0;
        const float* hsrc = (it == 0) ? query : q_buf;
        k_attn<<<dim3(32, B_), dim3(256), 0, stream>>>(
            qn_g, Kbf, Vt, Upart, rspart, out_a0, last);
        k_tail<<<dim3(B_ * N_), dim3(64), 0, stream>>>(
            Upart, rspart, hsrc, q_buf, wihT, whhT, gru_bih, gru_bhh,
            ln2_g, ln2_b, w1T, ffn_b1, w2T, ffn_b2,
            ln_q_g, ln_q_b, Wq, qn_g, out_q, last);
    }
}

// Round 4
// 296.563 us; speedup vs baseline: 1.4156x; 1.4156x over previous
//
#include <hip/hip_runtime.h>
#include <math.h>

#define B_ 32
#define HW_ 4096
#define N_ 16
#define C_ 128
#define F_ 512
#define ITERS_ 3
#define EPS_LN 1e-5f
#define EPS_ATTN 1e-5f

typedef __attribute__((ext_vector_type(8))) short short8;
typedef __attribute__((ext_vector_type(4))) float f32x4;

static __device__ __forceinline__ unsigned short f2b(float f) {
    union { float f; unsigned u; } v; v.f = f;
    unsigned r = v.u + 0x7fffu + ((v.u >> 16) & 1u);
    return (unsigned short)(r >> 16);
}
static __device__ __forceinline__ float blo(unsigned u) {
    union { unsigned u; float f; } v; v.u = u << 16; return v.f;
}
static __device__ __forceinline__ float bhi(unsigned u) {
    union { unsigned u; float f; } v; v.u = u & 0xffff0000u; return v.f;
}

// ---------------------------------------------------------------------------
// One-time prep.
// Blocks 0..31:    flat fp32->bf16 of Wk, Wv (for k_kvproj MFMA staging).
// Blocks 32..255:  transpose-packed bf16 of wih/whh/w1/w2 for k_tail.
// Blocks 256..287: qn_0 = (LN(query)*g+b) @ Wq^T * scale.
// Blocks 288..303: transpose-pack Wq (fp32) -> wqTf[g*128 + c] = Wq[c][4g..]
// ---------------------------------------------------------------------------
__global__ __launch_bounds__(256) void k_prep(
    const float* __restrict__ Wk, const float* __restrict__ Wv,
    const float* __restrict__ wih, const float* __restrict__ whh,
    const float* __restrict__ w1, const float* __restrict__ w2,
    unsigned short* __restrict__ Wk_bf, unsigned short* __restrict__ Wv_bf,
    unsigned short* __restrict__ wihT, unsigned short* __restrict__ whhT,
    unsigned short* __restrict__ w1T, unsigned short* __restrict__ w2T,
    const float* __restrict__ query, const float* __restrict__ lnqg,
    const float* __restrict__ lnqb, const float* __restrict__ Wq,
    float* __restrict__ wqTf, unsigned short* __restrict__ qn_g)
{
    __shared__ __align__(16) float xq[16 * 128];
    int tid = threadIdx.x;
    int blk = blockIdx.x;
    if (blk < 32) {
        int t = blk * 256 + tid;
        const float* src; unsigned short* dst; int off;
        if (t < 4096) { src = Wk; dst = Wk_bf; off = t; }
        else          { src = Wv; dst = Wv_bf; off = t - 4096; }
        float4 a = ((const float4*)src)[off];
        uint2 p;
        p.x = (unsigned)f2b(a.x) | ((unsigned)f2b(a.y) << 16);
        p.y = (unsigned)f2b(a.z) | ((unsigned)f2b(a.w) << 16);
        *(uint2*)(dst + off * 4) = p;
        return;
    }
    if (blk < 256) {
        const float* src; unsigned short* dst; int o, g, id, Cin;
        if (blk < 80) {         // wih: R=384, Cin=128
            id = (blk - 32) * 256 + tid;
            g = id / 384; o = id - g * 384;
            src = wih; dst = wihT; Cin = 128;
        } else if (blk < 128) { // whh: R=384
            id = (blk - 80) * 256 + tid;
            g = id / 384; o = id - g * 384;
            src = whh; dst = whhT; Cin = 128;
        } else if (blk < 192) { // w1: R=512, Cin=128
            id = (blk - 128) * 256 + tid;
            g = id >> 9; o = id & 511;
            src = w1; dst = w1T; Cin = 128;
        } else {                // w2: R=128, Cin=512
            id = (blk - 192) * 256 + tid;
            g = id >> 7; o = id & 127;
            src = w2; dst = w2T; Cin = 512;
        }
        float4 a = *(const float4*)(src + o * Cin + g * 4);
        uint2 p;
        p.x = (unsigned)f2b(a.x) | ((unsigned)f2b(a.y) << 16);
        p.y = (unsigned)f2b(a.z) | ((unsigned)f2b(a.w) << 16);
        *(uint2*)(dst + id * 4) = p;
        return;
    }
    if (blk >= 288) {
        // Wq fp32 transpose-pack: wqTf4[g*128 + c] = Wq[c][4g..4g+3]
        int t = (blk - 288) * 256 + tid;   // 0..4095
        int c = t & 127, g = t >> 7;       // g 0..31
        float4 a = *(const float4*)(Wq + c * 128 + g * 4);
        ((float4*)wqTf)[g * 128 + c] = a;
        return;
    }
    int b = blk - 256;
    int n = tid >> 4, part = tid & 15;
    int row = b * 16 + n;
    const float4* x4 = (const float4*)(query + row * 128 + part * 8);
    float4 x0 = x4[0], x1 = x4[1];
    float s = x0.x + x0.y + x0.z + x0.w + x1.x + x1.y + x1.z + x1.w;
    float ss = x0.x * x0.x + x0.y * x0.y + x0.z * x0.z + x0.w * x0.w +
               x1.x * x1.x + x1.y * x1.y + x1.z * x1.z + x1.w * x1.w;
    s += __shfl_xor(s, 1); s += __shfl_xor(s, 2); s += __shfl_xor(s, 4); s += __shfl_xor(s, 8);
    ss += __shfl_xor(ss, 1); ss += __shfl_xor(ss, 2); ss += __shfl_xor(ss, 4); ss += __shfl_xor(ss, 8);
    float mean = s * (1.f / 128.f);
    float var = ss * (1.f / 128.f) - mean * mean;
    float rstd = rsqrtf(var + EPS_LN);
    const float4* g4 = (const float4*)(lnqg + part * 8);
    const float4* b4 = (const float4*)(lnqb + part * 8);
    float4 g0 = g4[0], g1 = g4[1], bb0 = b4[0], bb1 = b4[1];
    float4 o0, o1;
    o0.x = (x0.x - mean) * rstd * g0.x + bb0.x;
    o0.y = (x0.y - mean) * rstd * g0.y + bb0.y;
    o0.z = (x0.z - mean) * rstd * g0.z + bb0.z;
    o0.w = (x0.w - mean) * rstd * g0.w + bb0.w;
    o1.x = (x1.x - mean) * rstd * g1.x + bb1.x;
    o1.y = (x1.y - mean) * rstd * g1.y + bb1.y;
    o1.z = (x1.z - mean) * rstd * g1.z + bb1.z;
    o1.w = (x1.w - mean) * rstd * g1.w + bb1.w;
    float4* xrow = (float4*)&xq[n * 128];
    xrow[part * 2] = o0;
    xrow[part * 2 + 1] = o1;
    __syncthreads();
    float o[8] = {0.f, 0.f, 0.f, 0.f, 0.f, 0.f, 0.f, 0.f};
    const float4* xv4 = (const float4*)&xq[n * 128];
#pragma unroll 4
    for (int j = 0; j < 32; j++) {
        float4 xv = xv4[j];
#pragma unroll
        for (int i = 0; i < 8; i++) {
            float4 w = ((const float4*)(Wq + (part * 8 + i) * 128))[j];
            o[i] += w.x * xv.x + w.y * xv.y + w.z * xv.z + w.w * xv.w;
        }
    }
    const float scale = 0.08838834764831845f;
#pragma unroll
    for (int i = 0; i < 8; i++)
        qn_g[row * 128 + part * 8 + i] = f2b(o[i] * scale);
}

// ---------------------------------------------------------------------------
// Kernel 1 (round-0 proven version, 54.6us): kv = LN(inp); K -> [b][hw][c];
// V -> [b][c][hw]. 64 rows/block. In-register LN. XOR-swizzled W_lds.
// ---------------------------------------------------------------------------
__global__ __launch_bounds__(256) void k_kvproj(
    const float* __restrict__ inp, const float* __restrict__ lng,
    const float* __restrict__ lnb, const unsigned short* __restrict__ Wk_bf,
    const unsigned short* __restrict__ Wv_bf, unsigned short* __restrict__ Kbf,
    unsigned short* __restrict__ Vt)
{
    __shared__ __align__(16) unsigned short W_lds[128 * 128];  // 32 KB
    __shared__ __align__(16) unsigned short T_lds[8960];       // 17.9 KB
    const int tid = threadIdx.x;
    const int wave = tid >> 6, lane = tid & 63;
    const int l15 = lane & 15, q4 = lane >> 4;
    const int kof = q4 * 8;
    const int tile0 = blockIdx.x * 64;
    const int b = tile0 >> 12;
    const int hwbase = tile0 & (HW_ - 1);

    const int srow = tid >> 1, shalf = tid & 1;
    const int sswz = srow & 7;

    // ---- in-register LN ----
    float x[4][8];
    {
        const float* rowp = inp + (tile0 + (wave << 4) + l15) * C_;
        float s = 0.f, ss = 0.f;
#pragma unroll
        for (int ks = 0; ks < 4; ks++) {
#pragma unroll
            for (int h = 0; h < 2; h++) {
                float4 v = *(const float4*)(rowp + ks * 32 + kof + h * 4);
                x[ks][h * 4 + 0] = v.x; x[ks][h * 4 + 1] = v.y;
                x[ks][h * 4 + 2] = v.z; x[ks][h * 4 + 3] = v.w;
                s += v.x + v.y + v.z + v.w;
                ss += v.x * v.x + v.y * v.y + v.z * v.z + v.w * v.w;
            }
        }
        s += __shfl_xor(s, 16);  s += __shfl_xor(s, 32);
        ss += __shfl_xor(ss, 16); ss += __shfl_xor(ss, 32);
        float mean = s * (1.f / 128.f);
        float var = ss * (1.f / 128.f) - mean * mean;
        float rstd = rsqrtf(var + EPS_LN);
#pragma unroll
        for (int ks = 0; ks < 4; ks++) {
#pragma unroll
            for (int h = 0; h < 2; h++) {
                float4 g = *(const float4*)(lng + ks * 32 + kof + h * 4);
                float4 bb = *(const float4*)(lnb + ks * 32 + kof + h * 4);
                x[ks][h * 4 + 0] = (x[ks][h * 4 + 0] - mean) * rstd * g.x + bb.x;
                x[ks][h * 4 + 1] = (x[ks][h * 4 + 1] - mean) * rstd * g.y + bb.y;
                x[ks][h * 4 + 2] = (x[ks][h * 4 + 2] - mean) * rstd * g.z + bb.z;
                x[ks][h * 4 + 3] = (x[ks][h * 4 + 3] - mean) * rstd * g.w + bb.w;
            }
        }
    }
    short8 af[4];
#pragma unroll
    for (int ks = 0; ks < 4; ks++) {
        union { short8 s8; unsigned u[4]; } p;
#pragma unroll
        for (int j = 0; j < 4; j++)
            p.u[j] = (unsigned)f2b(x[ks][2 * j]) | ((unsigned)f2b(x[ks][2 * j + 1]) << 16);
        af[ks] = p.s8;
    }

    // ---- stage Wk (swizzled) ----
    {
        const uint4* gW = (const uint4*)Wk_bf;
#pragma unroll
        for (int j = 0; j < 8; j++) {
            int c = shalf * 8 + j;
            uint4 w = gW[srow * 16 + c];
            *(uint4*)&W_lds[srow * 128 + (c ^ sswz) * 8] = w;
        }
    }
    __syncthreads();

    f32x4 acc[8];
    // ---- K phase ----
#pragma unroll
    for (int nt = 0; nt < 8; nt++) {
        acc[nt] = (f32x4){0.f, 0.f, 0.f, 0.f};
#pragma unroll
        for (int ks = 0; ks < 4; ks++) {
            short8 bf = *(const short8*)&W_lds[(nt * 16 + l15) * 128 + ((ks * 4 + q4) ^ (l15 & 7)) * 8];
            acc[nt] = __builtin_amdgcn_mfma_f32_16x16x32_bf16(af[ks], bf, acc[nt], 0, 0, 0);
        }
    }
    // K acc -> T [m][132]
#pragma unroll
    for (int nt = 0; nt < 8; nt++) {
        int c = nt * 16 + l15;
#pragma unroll
        for (int i = 0; i < 4; i++)
            T_lds[((wave << 4) + (q4 << 2) + i) * 132 + c] = f2b(acc[nt][i]);
    }
    __syncthreads();
    // K coalesced stores + stage Wv
    {
        int row = tid >> 2, part = tid & 3;
        uint4* dst = (uint4*)&Kbf[(b * HW_ + hwbase + row) * C_ + part * 32];
#pragma unroll
        for (int j = 0; j < 4; j++)
            dst[j] = *(const uint4*)&T_lds[row * 132 + part * 32 + j * 8];
    }
    {
        const uint4* gW = (const uint4*)Wv_bf;
#pragma unroll
        for (int j = 0; j < 8; j++) {
            int c = shalf * 8 + j;
            uint4 w = gW[srow * 16 + c];
            *(uint4*)&W_lds[srow * 128 + (c ^ sswz) * 8] = w;
        }
    }
    __syncthreads();
    // ---- V phase ----
#pragma unroll
    for (int nt = 0; nt < 8; nt++) {
        acc[nt] = (f32x4){0.f, 0.f, 0.f, 0.f};
#pragma unroll
        for (int ks = 0; ks < 4; ks++) {
            short8 bf = *(const short8*)&W_lds[(nt * 16 + l15) * 128 + ((ks * 4 + q4) ^ (l15 & 7)) * 8];
            acc[nt] = __builtin_amdgcn_mfma_f32_16x16x32_bf16(af[ks], bf, acc[nt], 0, 0, 0);
        }
    }
    __syncthreads();
    // V acc -> T2 transposed [c][70]
#pragma unroll
    for (int nt = 0; nt < 8; nt++) {
        int c = nt * 16 + l15;
#pragma unroll
        for (int i = 0; i < 4; i++)
            T_lds[c * 70 + (wave << 4) + (q4 << 2) + i] = f2b(acc[nt][i]);
    }
    __syncthreads();
    // V stores: vectorized from T2
    {
        int c = tid >> 1, half = tid & 1;
        uint4* dst = (uint4*)&Vt[(b * C_ + c) * HW_ + hwbase + half * 32];
#pragma unroll
        for (int j = 0; j < 4; j++)
            dst[j] = *(const uint4*)&T_lds[c * 70 + half * 32 + j * 8];
    }
}

// ---------------------------------------------------------------------------
// Kernel 2 (per iter): 256-thread blocks (4 waves), grid (32, B).
// ---------------------------------------------------------------------------
__global__ __launch_bounds__(256) void k_attn(
    const unsigned short* __restrict__ qn_g, const unsigned short* __restrict__ Kbf,
    const unsigned short* __restrict__ Vt, float* __restrict__ Upart,
    float* __restrict__ rspart, float* __restrict__ a0_out, int last)
{
    __shared__ __align__(16) float Ul[4][16 * 132];          // 33.8 KB
    __shared__ __align__(16) unsigned short Pb[4][16 * 40];  // 5.1 KB
    __shared__ float rsw[4][16];
    const int b = blockIdx.y, chunk = blockIdx.x;
    const int tid = threadIdx.x;
    const int wave = tid >> 6, lane = tid & 63;
    const int l15 = lane & 15, q4 = lane >> 4;
    const int kof = q4 * 8;
    const int hwb = chunk * 128 + wave * 32;

    short8 aq[4];
#pragma unroll
    for (int ks = 0; ks < 4; ks++)
        aq[ks] = *(const short8*)&qn_g[(b * 16 + l15) * 128 + ks * 32 + kof];
    short8 av[8];
#pragma unroll
    for (int ct = 0; ct < 8; ct++)
        av[ct] = *(const short8*)&Vt[(b * C_ + ct * 16 + l15) * HW_ + hwb + kof];

    unsigned short* Pw = &Pb[wave][0];
    float rs[4] = {0.f, 0.f, 0.f, 0.f};
#pragma unroll
    for (int s = 0; s < 2; s++) {
        int hwt = hwb + s * 16;
        f32x4 sa = {0.f, 0.f, 0.f, 0.f};
#pragma unroll
        for (int ks = 0; ks < 4; ks++) {
            short8 bk = *(const short8*)&Kbf[(b * HW_ + hwt + l15) * C_ + ks * 32 + kof];
            sa = __builtin_amdgcn_mfma_f32_16x16x32_bf16(aq[ks], bk, sa, 0, 0, 0);
        }
        float mx = fmaxf(fmaxf(sa[0], sa[1]), fmaxf(sa[2], sa[3]));
        mx = fmaxf(mx, __shfl_xor(mx, 16));
        mx = fmaxf(mx, __shfl_xor(mx, 32));
        float e[4]; float ssum = 0.f;
#pragma unroll
        for (int i = 0; i < 4; i++) { e[i] = __expf(sa[i] - mx); ssum += e[i]; }
        ssum += __shfl_xor(ssum, 16);
        ssum += __shfl_xor(ssum, 32);
        float inv = 1.f / ssum;
#pragma unroll
        for (int i = 0; i < 4; i++) {
            float a0v = e[i] * inv;
            rs[i] += a0v;
            if (last) a0_out[(b * 16 + q4 * 4 + i) * HW_ + hwt + l15] = a0v;
            Pw[(q4 * 4 + i) * 40 + s * 16 + l15] = f2b(a0v);
        }
    }
#pragma unroll
    for (int i = 0; i < 4; i++) {
        rs[i] += __shfl_xor(rs[i], 1);
        rs[i] += __shfl_xor(rs[i], 2);
        rs[i] += __shfl_xor(rs[i], 4);
        rs[i] += __shfl_xor(rs[i], 8);
    }
    if (l15 == 0) {
#pragma unroll
        for (int i = 0; i < 4; i++) rsw[wave][q4 * 4 + i] = rs[i];
    }
    short8 bp = *(const short8*)&Pw[l15 * 40 + kof];
#pragma unroll
    for (int ct = 0; ct < 8; ct++) {
        f32x4 ua = __builtin_amdgcn_mfma_f32_16x16x32_bf16(av[ct], bp, (f32x4){0.f, 0.f, 0.f, 0.f}, 0, 0, 0);
        *(f32x4*)&Ul[wave][l15 * 132 + ct * 16 + (q4 << 2)] = ua;
    }
    __syncthreads();
    {
        float* up = Upart + (b * 32 + chunk) * 2048;
#pragma unroll
        for (int k = 0; k < 8; k++) {
            int idx = tid + k * 256;          // idx = q*128 + c
            int q = idx >> 7, c = idx & 127;
            up[idx] = Ul[0][q * 132 + c] + Ul[1][q * 132 + c] +
                      Ul[2][q * 132 + c] + Ul[3][q * 132 + c];
        }
        if (tid < 16)
            rspart[(b * 32 + chunk) * 16 + tid] =
                rsw[0][tid] + rsw[1][tid] + rsw[2][tid] + rsw[3][tid];
    }
}

// ---------------------------------------------------------------------------
// Kernel 3 v4 (per iter): one row per block, 1024 threads (16 waves).
// v2/v3 post-mortem: wave-per-row = 2 waves/CU, everything L2-served, 65us of
// pure exposed latency regardless of coalescing. Fix = TLP: 2 blocks/CU x 16
// waves. Every GEMV phase splits outputs x K-slices over all 1024 threads
// with coalesced packed weights; partials reduced via LDS red[1024].
// LN stats computed redundantly per-wave (no single-wave serialization).
// ---------------------------------------------------------------------------
__global__ __launch_bounds__(1024, 4) void k_tail(
    const float* __restrict__ Upart, const float* __restrict__ rspart,
    const float* __restrict__ hsrc, float* __restrict__ q_buf,
    const unsigned short* __restrict__ wihT, const unsigned short* __restrict__ whhT,
    const float* __restrict__ bih, const float* __restrict__ bhh,
    const float* __restrict__ ln2g, const float* __restrict__ ln2b,
    const unsigned short* __restrict__ w1T, const float* __restrict__ b1,
    const unsigned short* __restrict__ w2T, const float* __restrict__ b2,
    const float* __restrict__ lnqg, const float* __restrict__ lnqb,
    const float* __restrict__ wqTf, unsigned short* __restrict__ qn_g,
    float* __restrict__ out_q, int last)
{
    __shared__ __align__(16) float red[1024];
    __shared__ __align__(16) float u_l[128];
    __shared__ __align__(16) float h_l[128];
    __shared__ __align__(16) float y_l[128];
    __shared__ __align__(16) float z_l[128];
    __shared__ __align__(16) float g_l[768];
    __shared__ __align__(16) float h1_l[512];
    __shared__ float srs;
    const int tid = threadIdx.x;
    const int row = blockIdx.x;
    const int b = row >> 4, q = row & 15;

    // ---- Phase 0: Upart 8-way partial reduce; h load; rspart reduce ----
    {
        int c = tid & 127, h = tid >> 7;   // h in 0..7
        const float* up = Upart + (b * 32 + h * 4) * 2048 + q * 128 + c;
        float part = 0.f;
#pragma unroll
        for (int ch = 0; ch < 4; ch++) part += up[ch * 2048];
        red[tid] = part;
        if (tid < 128) h_l[tid] = hsrc[row * 128 + tid];
        if (tid >= 128 && tid < 160) {
            int t = tid - 128;
            float v = rspart[(b * 32 + t) * 16 + q];
            v += __shfl_xor(v, 1); v += __shfl_xor(v, 2); v += __shfl_xor(v, 4);
            v += __shfl_xor(v, 8); v += __shfl_xor(v, 16);
            if (t == 0) srs = v;
        }
    }
    __syncthreads();
    // ---- u ----
    if (tid < 128) {
        float s = 0.f;
#pragma unroll
        for (int h = 0; h < 8; h++) s += red[tid + 128 * h];
        u_l[tid] = s / (srs + EPS_ATTN);
    }
    __syncthreads();
    // ---- GRU gates: 768 outputs, 1 per thread, coalesced packed W ----
    if (tid < 768) {
        int o = tid;
        const uint2* wp;
        const float* src;
        float bias;
        if (o < 384) { wp = (const uint2*)wihT + o; src = u_l; bias = bih[o]; }
        else         { wp = (const uint2*)whhT + (o - 384); src = h_l; bias = bhh[o - 384]; }
        float acc = 0.f;
#pragma unroll 4
        for (int g = 0; g < 32; g++) {
            uint2 w = wp[g * 384];
            float4 sv = *(const float4*)&src[g * 4];
            acc += blo(w.x) * sv.x + bhi(w.x) * sv.y
                 + blo(w.y) * sv.z + bhi(w.y) * sv.w;
        }
        g_l[o] = acc + bias;
    }
    __syncthreads();
    // ---- GRU elementwise ----
    if (tid < 128) {
        int c = tid;
        float ir = g_l[c], iz = g_l[128 + c], in_ = g_l[256 + c];
        float hr = g_l[384 + c], hz = g_l[512 + c], hn = g_l[640 + c];
        float rr = 1.f / (1.f + expf(-(ir + hr)));
        float zz = 1.f / (1.f + expf(-(iz + hz)));
        float nn = tanhf(in_ + rr * hn);
        y_l[c] = (1.f - zz) * nn + zz * h_l[c];
    }
    __syncthreads();
    // ---- LN2: per-wave redundant stats (no extra barrier) ----
    {
        int l = tid & 63;
        float v0 = y_l[l], v1 = y_l[l + 64];
        float s = v0 + v1, ss = v0 * v0 + v1 * v1;
#pragma unroll
        for (int off = 1; off < 64; off <<= 1) {
            s += __shfl_xor(s, off);
            ss += __shfl_xor(ss, off);
        }
        float mean = s * (1.f / 128.f);
        float var = ss * (1.f / 128.f) - mean * mean;
        float rstd = rsqrtf(var + EPS_LN);
        if (tid < 128)
            z_l[tid] = (y_l[tid] - mean) * rstd * ln2g[tid] + ln2b[tid];
    }
    __syncthreads();
    // ---- FFN1: f = tid&511, khalf = tid>>9 (16 groups each) ----
    {
        int f = tid & 511, hh = tid >> 9;
        const uint2* wp = (const uint2*)w1T + f;
        float acc = 0.f;
#pragma unroll 4
        for (int j = 0; j < 16; j++) {
            int g = hh * 16 + j;
            uint2 w = wp[g * 512];
            float4 zv = *(const float4*)&z_l[g * 4];
            acc += blo(w.x) * zv.x + bhi(w.x) * zv.y
                 + blo(w.y) * zv.z + bhi(w.y) * zv.w;
        }
        red[tid] = acc;   // tid = hh*512 + f
    }
    __syncthreads();
    if (tid < 512)
        h1_l[tid] = fmaxf(red[tid] + red[tid + 512] + b1[tid], 0.f);
    __syncthreads();
    // ---- FFN2: c = tid&127, k8 = tid>>7 (16 groups each of 512-K) ----
    {
        int c = tid & 127, h8 = tid >> 7;
        const uint2* wp = (const uint2*)w2T + c;
        float acc = 0.f;
#pragma unroll 4
        for (int j = 0; j < 16; j++) {
            int g = h8 * 16 + j;
            uint2 w = wp[g * 128];
            float4 hv = *(const float4*)&h1_l[g * 4];
            acc += blo(w.x) * hv.x + bhi(w.x) * hv.y
                 + blo(w.y) * hv.z + bhi(w.y) * hv.w;
        }
        red[tid] = acc;   // tid = h8*128 + c
    }
    __syncthreads();
    if (tid < 128) {
        float f2 = 0.f;
#pragma unroll
        for (int k = 0; k < 8; k++) f2 += red[tid + 128 * k];
        float qn = y_l[tid] + f2 + b2[tid];
        u_l[tid] = qn;                      // reuse u_l as qnew buffer
        q_buf[row * 128 + tid] = qn;
        if (last) out_q[row * 128 + tid] = qn;
    }
    if (last) return;
    __syncthreads();
    // ---- LN(q_new): per-wave redundant stats ----
    {
        int l = tid & 63;
        float v0 = u_l[l], v1 = u_l[l + 64];
        float s = v0 + v1, ss = v0 * v0 + v1 * v1;
#pragma unroll
        for (int off = 1; off < 64; off <<= 1) {
            s += __shfl_xor(s, off);
            ss += __shfl_xor(ss, off);
        }
        float mean = s * (1.f / 128.f);
        float var = ss * (1.f / 128.f) - mean * mean;
        float rstd = rsqrtf(var + EPS_LN);
        if (tid < 128)
            z_l[tid] = (u_l[tid] - mean) * rstd * lnqg[tid] + lnqb[tid];
    }
    __syncthreads();
    // ---- qn_next = LN(q_new) @ Wq^T * scale (fp32 packed wqTf) ----
    {
        int c = tid & 127, h8 = tid >> 7;
        const float4* wp = (const float4*)wqTf + c;
        float acc = 0.f;
#pragma unroll
        for (int j = 0; j < 4; j++) {
            int g = h8 * 4 + j;
            float4 w = wp[g * 128];
            float4 zv = *(const float4*)&z_l[g * 4];
            acc += w.x * zv.x + w.y * zv.y + w.z * zv.z + w.w * zv.w;
        }
        red[tid] = acc;
    }
    __syncthreads();
    if (tid < 128) {
        float qa = 0.f;
#pragma unroll
        for (int k = 0; k < 8; k++) qa += red[tid + 128 * k];
        qn_g[row * 128 + tid] = f2b(qa * 0.08838834764831845f);
    }
}

// ---------------------------------------------------------------------------
extern "C" void kernel_launch(void* const* d_in, const int* in_sizes, int n_in,
                              void* d_out, int out_size, void* d_ws, size_t ws_size,
                              hipStream_t stream) {
    const float* inp     = (const float*)d_in[0];
    const float* query   = (const float*)d_in[1];
    const float* ln_kv_g = (const float*)d_in[2];
    const float* ln_kv_b = (const float*)d_in[3];
    const float* Wk      = (const float*)d_in[4];
    const float* Wv      = (const float*)d_in[5];
    const float* ln_q_g  = (const float*)d_in[6];
    const float* ln_q_b  = (const float*)d_in[7];
    const float* Wq      = (const float*)d_in[8];
    const float* gru_wih = (const float*)d_in[9];
    const float* gru_whh = (const float*)d_in[10];
    const float* gru_bih = (const float*)d_in[11];
    const float* gru_bhh = (const float*)d_in[12];
    const float* ln2_g   = (const float*)d_in[13];
    const float* ln2_b   = (const float*)d_in[14];
    const float* ffn_w1  = (const float*)d_in[15];
    const float* ffn_b1  = (const float*)d_in[16];
    const float* ffn_w2  = (const float*)d_in[17];
    const float* ffn_b2  = (const float*)d_in[18];

    char* ws = (char*)d_ws;
    unsigned short* Kbf    = (unsigned short*)ws;                  // 33554432
    unsigned short* Vt     = (unsigned short*)(ws + 33554432);     // 33554432
    float* q_buf           = (float*)(ws + 67108864);              // 262144
    float* Upart           = (float*)(ws + 67371008);              // 8388608
    float* rspart          = (float*)(ws + 75759616);              // 65536
    unsigned short* qn_g   = (unsigned short*)(ws + 75825152);     // 131072
    unsigned short* Wk_bf  = (unsigned short*)(ws + 75956224);     // 32768
    unsigned short* Wv_bf  = (unsigned short*)(ws + 75988992);     // 32768
    unsigned short* wihT   = (unsigned short*)(ws + 76021760);     // 98304
    unsigned short* whhT   = (unsigned short*)(ws + 76120064);     // 98304
    unsigned short* w1T    = (unsigned short*)(ws + 76218368);     // 131072
    unsigned short* w2T    = (unsigned short*)(ws + 76349440);     // 131072
    float* wqTf            = (float*)(ws + 76480512);              // 65536

    float* out_q  = (float*)d_out;
    float* out_a0 = out_q + B_ * N_ * C_;

    k_prep<<<dim3(304), dim3(256), 0, stream>>>(
        Wk, Wv, gru_wih, gru_whh, ffn_w1, ffn_w2,
        Wk_bf, Wv_bf, wihT, whhT, w1T, w2T,
        query, ln_q_g, ln_q_b, Wq, wqTf, qn_g);
    k_kvproj<<<dim3((B_ * HW_) / 64), dim3(256), 0, stream>>>(
        inp, ln_kv_g, ln_kv_b, Wk_bf, Wv_bf, Kbf, Vt);

    for (int it = 0; it < ITERS_; it++) {
        int last = (it == ITERS_ - 1) ? 1 : 0;
        const float* hsrc = (it == 0) ? query : q_buf;
        k_attn<<<dim3(32, B_), dim3(256), 0, stream>>>(
            qn_g, Kbf, Vt, Upart, rspart, out_a0, last);
        k_tail<<<dim3(B_ * N_), dim3(1024), 0, stream>>>(
            Upart, rspart, hsrc, q_buf, wihT, whhT, gru_bih, gru_bhh,
            ln2_g, ln2_b, w1T, ffn_b1, w2T, ffn_b2,
            ln_q_g, ln_q_b, wqTf, qn_g, out_q, last);
    }
}

// Round 5
// 287.054 us; speedup vs baseline: 1.4625x; 1.0331x over previous
//
#include <hip/hip_runtime.h>
#include <math.h>

#define B_ 32
#define HW_ 4096
#define N_ 16
#define C_ 128
#define F_ 512
#define ITERS_ 3
#define EPS_LN 1e-5f
#define EPS_ATTN 1e-5f

typedef __attribute__((ext_vector_type(8))) short short8;
typedef __attribute__((ext_vector_type(4))) float f32x4;

static __device__ __forceinline__ unsigned short f2b(float f) {
    union { float f; unsigned u; } v; v.f = f;
    unsigned r = v.u + 0x7fffu + ((v.u >> 16) & 1u);
    return (unsigned short)(r >> 16);
}
static __device__ __forceinline__ float blo(unsigned u) {
    union { unsigned u; float f; } v; v.u = u << 16; return v.f;
}
static __device__ __forceinline__ float bhi(unsigned u) {
    union { unsigned u; float f; } v; v.u = u & 0xffff0000u; return v.f;
}
// async global->LDS, 16B per lane; LDS dest is wave-uniform base + lane*16
static __device__ __forceinline__ void gload_lds16(const void* g, void* l) {
    __builtin_amdgcn_global_load_lds(
        (const __attribute__((address_space(1))) unsigned int*)g,
        (__attribute__((address_space(3))) unsigned int*)l, 16, 0, 0);
}

// ---------------------------------------------------------------------------
// One-time prep.
// Blocks 0..31:    Wk,Wv fp32->bf16 PRE-SWIZZLED into the kvproj LDS layout:
//                  dst[r*128 + ((cg ^ (r&7))<<3) + half*4] = W[r][cg*8+half*4..]
//                  so kvproj can stage with linear async global_load_lds.
// Blocks 32..255:  transpose-packed bf16 of wih/whh/w1/w2 for k_tail.
// Blocks 256..287: qn_0 = (LN(query)*g+b) @ Wq^T * scale.
// Blocks 288..303: transpose-pack Wq (fp32) -> wqTf[g*128 + c] = Wq[c][4g..]
// ---------------------------------------------------------------------------
__global__ __launch_bounds__(256) void k_prep(
    const float* __restrict__ Wk, const float* __restrict__ Wv,
    const float* __restrict__ wih, const float* __restrict__ whh,
    const float* __restrict__ w1, const float* __restrict__ w2,
    unsigned short* __restrict__ Wk_sw, unsigned short* __restrict__ Wv_sw,
    unsigned short* __restrict__ wihT, unsigned short* __restrict__ whhT,
    unsigned short* __restrict__ w1T, unsigned short* __restrict__ w2T,
    const float* __restrict__ query, const float* __restrict__ lnqg,
    const float* __restrict__ lnqb, const float* __restrict__ Wq,
    float* __restrict__ wqTf, unsigned short* __restrict__ qn_g)
{
    __shared__ __align__(16) float xq[16 * 128];
    int tid = threadIdx.x;
    int blk = blockIdx.x;
    if (blk < 32) {
        int t = blk * 256 + tid;           // float4-group id, 0..8191
        const float* src; unsigned short* dst; int off;
        if (t < 4096) { src = Wk; dst = Wk_sw; off = t; }
        else          { src = Wv; dst = Wv_sw; off = t - 4096; }
        float4 a = ((const float4*)src)[off];
        uint2 p;
        p.x = (unsigned)f2b(a.x) | ((unsigned)f2b(a.y) << 16);
        p.y = (unsigned)f2b(a.z) | ((unsigned)f2b(a.w) << 16);
        int r = off >> 5;                  // row 0..127
        int j = off & 31;                  // 4-short group within row
        int cg = j >> 1, half = j & 1;     // 8-short col-group + half
        int dsw = r * 128 + (((cg ^ (r & 7)) << 3)) + (half << 2);
        *(uint2*)(dst + dsw) = p;
        return;
    }
    if (blk < 256) {
        const float* src; unsigned short* dst; int o, g, id, Cin;
        if (blk < 80) {         // wih: R=384, Cin=128
            id = (blk - 32) * 256 + tid;
            g = id / 384; o = id - g * 384;
            src = wih; dst = wihT; Cin = 128;
        } else if (blk < 128) { // whh: R=384
            id = (blk - 80) * 256 + tid;
            g = id / 384; o = id - g * 384;
            src = whh; dst = whhT; Cin = 128;
        } else if (blk < 192) { // w1: R=512, Cin=128
            id = (blk - 128) * 256 + tid;
            g = id >> 9; o = id & 511;
            src = w1; dst = w1T; Cin = 128;
        } else {                // w2: R=128, Cin=512
            id = (blk - 192) * 256 + tid;
            g = id >> 7; o = id & 127;
            src = w2; dst = w2T; Cin = 512;
        }
        float4 a = *(const float4*)(src + o * Cin + g * 4);
        uint2 p;
        p.x = (unsigned)f2b(a.x) | ((unsigned)f2b(a.y) << 16);
        p.y = (unsigned)f2b(a.z) | ((unsigned)f2b(a.w) << 16);
        *(uint2*)(dst + id * 4) = p;
        return;
    }
    if (blk >= 288) {
        int t = (blk - 288) * 256 + tid;   // 0..4095
        int c = t & 127, g = t >> 7;       // g 0..31
        float4 a = *(const float4*)(Wq + c * 128 + g * 4);
        ((float4*)wqTf)[g * 128 + c] = a;
        return;
    }
    int b = blk - 256;
    int n = tid >> 4, part = tid & 15;
    int row = b * 16 + n;
    const float4* x4 = (const float4*)(query + row * 128 + part * 8);
    float4 x0 = x4[0], x1 = x4[1];
    float s = x0.x + x0.y + x0.z + x0.w + x1.x + x1.y + x1.z + x1.w;
    float ss = x0.x * x0.x + x0.y * x0.y + x0.z * x0.z + x0.w * x0.w +
               x1.x * x1.x + x1.y * x1.y + x1.z * x1.z + x1.w * x1.w;
    s += __shfl_xor(s, 1); s += __shfl_xor(s, 2); s += __shfl_xor(s, 4); s += __shfl_xor(s, 8);
    ss += __shfl_xor(ss, 1); ss += __shfl_xor(ss, 2); ss += __shfl_xor(ss, 4); ss += __shfl_xor(ss, 8);
    float mean = s * (1.f / 128.f);
    float var = ss * (1.f / 128.f) - mean * mean;
    float rstd = rsqrtf(var + EPS_LN);
    const float4* g4 = (const float4*)(lnqg + part * 8);
    const float4* b4 = (const float4*)(lnqb + part * 8);
    float4 g0 = g4[0], g1 = g4[1], bb0 = b4[0], bb1 = b4[1];
    float4 o0, o1;
    o0.x = (x0.x - mean) * rstd * g0.x + bb0.x;
    o0.y = (x0.y - mean) * rstd * g0.y + bb0.y;
    o0.z = (x0.z - mean) * rstd * g0.z + bb0.z;
    o0.w = (x0.w - mean) * rstd * g0.w + bb0.w;
    o1.x = (x1.x - mean) * rstd * g1.x + bb1.x;
    o1.y = (x1.y - mean) * rstd * g1.y + bb1.y;
    o1.z = (x1.z - mean) * rstd * g1.z + bb1.z;
    o1.w = (x1.w - mean) * rstd * g1.w + bb1.w;
    float4* xrow = (float4*)&xq[n * 128];
    xrow[part * 2] = o0;
    xrow[part * 2 + 1] = o1;
    __syncthreads();
    float o[8] = {0.f, 0.f, 0.f, 0.f, 0.f, 0.f, 0.f, 0.f};
    const float4* xv4 = (const float4*)&xq[n * 128];
#pragma unroll 4
    for (int j = 0; j < 32; j++) {
        float4 xv = xv4[j];
#pragma unroll
        for (int i = 0; i < 8; i++) {
            float4 w = ((const float4*)(Wq + (part * 8 + i) * 128))[j];
            o[i] += w.x * xv.x + w.y * xv.y + w.z * xv.z + w.w * xv.w;
        }
    }
    const float scale = 0.08838834764831845f;
#pragma unroll
    for (int i = 0; i < 8; i++)
        qn_g[row * 128 + part * 8 + i] = f2b(o[i] * scale);
}

// ---------------------------------------------------------------------------
// Kernel 1 v3: 128 rows/block, 512 threads (8 waves), grid 1024.
// W pre-swizzled in global -> staging is LINEAR async global_load_lds (16B),
// issued before LN (Wk) / after K-store (Wv) so HBM/L2 latency hides under
// compute. 4 barriers (was 5). LDS 65.8KB -> 2 blocks/CU = 16 waves/CU
// (was 8). W staged once per 128 rows (was per 64).
// ---------------------------------------------------------------------------
__global__ __launch_bounds__(512, 4) void k_kvproj(
    const float* __restrict__ inp, const float* __restrict__ lng,
    const float* __restrict__ lnb, const unsigned short* __restrict__ Wk_sw,
    const unsigned short* __restrict__ Wv_sw, unsigned short* __restrict__ Kbf,
    unsigned short* __restrict__ Vt)
{
    __shared__ __align__(16) unsigned short W_lds[128 * 128];  // 32 KB
    __shared__ __align__(16) unsigned short T_lds[128 * 132];  // 33.8 KB
    const int tid = threadIdx.x;
    const int wave = tid >> 6, lane = tid & 63;
    const int l15 = lane & 15, q4 = lane >> 4;
    const int kof = q4 * 8;
    const int tile0 = blockIdx.x * 128;
    const int b = tile0 >> 12;
    const int hwbase = tile0 & (HW_ - 1);

    // ---- issue Wk -> LDS async (linear; swizzle pre-baked in global) ----
    {
        const char* gw = (const char*)Wk_sw + wave * 4096 + lane * 16;
        char* lw = (char*)W_lds + wave * 4096;
#pragma unroll
        for (int j = 0; j < 4; j++)
            gload_lds16(gw + j * 1024, lw + j * 1024);
    }

    // ---- in-register LN (wave handles rows tile0 + wave*16 + l15) ----
    float x[4][8];
    {
        const float* rowp = inp + (tile0 + (wave << 4) + l15) * C_;
        float s = 0.f, ss = 0.f;
#pragma unroll
        for (int ks = 0; ks < 4; ks++) {
#pragma unroll
            for (int h = 0; h < 2; h++) {
                float4 v = *(const float4*)(rowp + ks * 32 + kof + h * 4);
                x[ks][h * 4 + 0] = v.x; x[ks][h * 4 + 1] = v.y;
                x[ks][h * 4 + 2] = v.z; x[ks][h * 4 + 3] = v.w;
                s += v.x + v.y + v.z + v.w;
                ss += v.x * v.x + v.y * v.y + v.z * v.z + v.w * v.w;
            }
        }
        s += __shfl_xor(s, 16);  s += __shfl_xor(s, 32);
        ss += __shfl_xor(ss, 16); ss += __shfl_xor(ss, 32);
        float mean = s * (1.f / 128.f);
        float var = ss * (1.f / 128.f) - mean * mean;
        float rstd = rsqrtf(var + EPS_LN);
#pragma unroll
        for (int ks = 0; ks < 4; ks++) {
#pragma unroll
            for (int h = 0; h < 2; h++) {
                float4 g = *(const float4*)(lng + ks * 32 + kof + h * 4);
                float4 bb = *(const float4*)(lnb + ks * 32 + kof + h * 4);
                x[ks][h * 4 + 0] = (x[ks][h * 4 + 0] - mean) * rstd * g.x + bb.x;
                x[ks][h * 4 + 1] = (x[ks][h * 4 + 1] - mean) * rstd * g.y + bb.y;
                x[ks][h * 4 + 2] = (x[ks][h * 4 + 2] - mean) * rstd * g.z + bb.z;
                x[ks][h * 4 + 3] = (x[ks][h * 4 + 3] - mean) * rstd * g.w + bb.w;
            }
        }
    }
    short8 af[4];
#pragma unroll
    for (int ks = 0; ks < 4; ks++) {
        union { short8 s8; unsigned u[4]; } p;
#pragma unroll
        for (int j = 0; j < 4; j++)
            p.u[j] = (unsigned)f2b(x[ks][2 * j]) | ((unsigned)f2b(x[ks][2 * j + 1]) << 16);
        af[ks] = p.s8;
    }

    __syncthreads();   // [1] Wk in LDS (compiler drains vmcnt at barrier)

    // ---- K phase ----
    f32x4 acc[8];
#pragma unroll
    for (int nt = 0; nt < 8; nt++) {
        acc[nt] = (f32x4){0.f, 0.f, 0.f, 0.f};
#pragma unroll
        for (int ks = 0; ks < 4; ks++) {
            short8 bf = *(const short8*)&W_lds[(nt * 16 + l15) * 128 + ((ks * 4 + q4) ^ (l15 & 7)) * 8];
            acc[nt] = __builtin_amdgcn_mfma_f32_16x16x32_bf16(af[ks], bf, acc[nt], 0, 0, 0);
        }
    }
    // K acc -> T [row][132]
#pragma unroll
    for (int nt = 0; nt < 8; nt++) {
        int c = nt * 16 + l15;
#pragma unroll
        for (int i = 0; i < 4; i++)
            T_lds[((wave << 4) + (q4 << 2) + i) * 132 + c] = f2b(acc[nt][i]);
    }
    __syncthreads();   // [2] T ready; all K-MFMA W reads done

    // K coalesced stores (512 thr: row=tid>>2, part=tid&3)
    {
        int row = tid >> 2, part = tid & 3;
        uint4* dst = (uint4*)&Kbf[(b * HW_ + hwbase + row) * C_ + part * 32];
#pragma unroll
        for (int j = 0; j < 4; j++)
            dst[j] = *(const uint4*)&T_lds[row * 132 + part * 32 + j * 8];
    }
    // ---- issue Wv -> LDS async (W_lds free after barrier 2) ----
    {
        const char* gw = (const char*)Wv_sw + wave * 4096 + lane * 16;
        char* lw = (char*)W_lds + wave * 4096;
#pragma unroll
        for (int j = 0; j < 4; j++)
            gload_lds16(gw + j * 1024, lw + j * 1024);
    }
    __syncthreads();   // [3] Wv in LDS; all T reads (K stores) done

    // ---- V phase ----
#pragma unroll
    for (int nt = 0; nt < 8; nt++) {
        acc[nt] = (f32x4){0.f, 0.f, 0.f, 0.f};
#pragma unroll
        for (int ks = 0; ks < 4; ks++) {
            short8 bf = *(const short8*)&W_lds[(nt * 16 + l15) * 128 + ((ks * 4 + q4) ^ (l15 & 7)) * 8];
            acc[nt] = __builtin_amdgcn_mfma_f32_16x16x32_bf16(af[ks], bf, acc[nt], 0, 0, 0);
        }
    }
    // V acc -> T2 transposed [c][132] (rows disjoint per wave)
#pragma unroll
    for (int nt = 0; nt < 8; nt++) {
        int c = nt * 16 + l15;
#pragma unroll
        for (int i = 0; i < 4; i++)
            T_lds[c * 132 + (wave << 4) + (q4 << 2) + i] = f2b(acc[nt][i]);
    }
    __syncthreads();   // [4]

    // V stores: vectorized from T2 (512 thr: c=tid>>2, part=tid&3)
    {
        int c = tid >> 2, part = tid & 3;
        uint4* dst = (uint4*)&Vt[(b * C_ + c) * HW_ + hwbase + part * 32];
#pragma unroll
        for (int j = 0; j < 4; j++)
            dst[j] = *(const uint4*)&T_lds[c * 132 + part * 32 + j * 8];
    }
}

// ---------------------------------------------------------------------------
// Kernel 2 (per iter): 256-thread blocks (4 waves), grid (32, B).
// ---------------------------------------------------------------------------
__global__ __launch_bounds__(256) void k_attn(
    const unsigned short* __restrict__ qn_g, const unsigned short* __restrict__ Kbf,
    const unsigned short* __restrict__ Vt, float* __restrict__ Upart,
    float* __restrict__ rspart, float* __restrict__ a0_out, int last)
{
    __shared__ __align__(16) float Ul[4][16 * 132];          // 33.8 KB
    __shared__ __align__(16) unsigned short Pb[4][16 * 40];  // 5.1 KB
    __shared__ float rsw[4][16];
    const int b = blockIdx.y, chunk = blockIdx.x;
    const int tid = threadIdx.x;
    const int wave = tid >> 6, lane = tid & 63;
    const int l15 = lane & 15, q4 = lane >> 4;
    const int kof = q4 * 8;
    const int hwb = chunk * 128 + wave * 32;

    short8 aq[4];
#pragma unroll
    for (int ks = 0; ks < 4; ks++)
        aq[ks] = *(const short8*)&qn_g[(b * 16 + l15) * 128 + ks * 32 + kof];
    short8 av[8];
#pragma unroll
    for (int ct = 0; ct < 8; ct++)
        av[ct] = *(const short8*)&Vt[(b * C_ + ct * 16 + l15) * HW_ + hwb + kof];

    unsigned short* Pw = &Pb[wave][0];
    float rs[4] = {0.f, 0.f, 0.f, 0.f};
#pragma unroll
    for (int s = 0; s < 2; s++) {
        int hwt = hwb + s * 16;
        f32x4 sa = {0.f, 0.f, 0.f, 0.f};
#pragma unroll
        for (int ks = 0; ks < 4; ks++) {
            short8 bk = *(const short8*)&Kbf[(b * HW_ + hwt + l15) * C_ + ks * 32 + kof];
            sa = __builtin_amdgcn_mfma_f32_16x16x32_bf16(aq[ks], bk, sa, 0, 0, 0);
        }
        float mx = fmaxf(fmaxf(sa[0], sa[1]), fmaxf(sa[2], sa[3]));
        mx = fmaxf(mx, __shfl_xor(mx, 16));
        mx = fmaxf(mx, __shfl_xor(mx, 32));
        float e[4]; float ssum = 0.f;
#pragma unroll
        for (int i = 0; i < 4; i++) { e[i] = __expf(sa[i] - mx); ssum += e[i]; }
        ssum += __shfl_xor(ssum, 16);
        ssum += __shfl_xor(ssum, 32);
        float inv = 1.f / ssum;
#pragma unroll
        for (int i = 0; i < 4; i++) {
            float a0v = e[i] * inv;
            rs[i] += a0v;
            if (last) a0_out[(b * 16 + q4 * 4 + i) * HW_ + hwt + l15] = a0v;
            Pw[(q4 * 4 + i) * 40 + s * 16 + l15] = f2b(a0v);
        }
    }
#pragma unroll
    for (int i = 0; i < 4; i++) {
        rs[i] += __shfl_xor(rs[i], 1);
        rs[i] += __shfl_xor(rs[i], 2);
        rs[i] += __shfl_xor(rs[i], 4);
        rs[i] += __shfl_xor(rs[i], 8);
    }
    if (l15 == 0) {
#pragma unroll
        for (int i = 0; i < 4; i++) rsw[wave][q4 * 4 + i] = rs[i];
    }
    short8 bp = *(const short8*)&Pw[l15 * 40 + kof];
#pragma unroll
    for (int ct = 0; ct < 8; ct++) {
        f32x4 ua = __builtin_amdgcn_mfma_f32_16x16x32_bf16(av[ct], bp, (f32x4){0.f, 0.f, 0.f, 0.f}, 0, 0, 0);
        *(f32x4*)&Ul[wave][l15 * 132 + ct * 16 + (q4 << 2)] = ua;
    }
    __syncthreads();
    {
        float* up = Upart + (b * 32 + chunk) * 2048;
#pragma unroll
        for (int k = 0; k < 8; k++) {
            int idx = tid + k * 256;          // idx = q*128 + c
            int q = idx >> 7, c = idx & 127;
            up[idx] = Ul[0][q * 132 + c] + Ul[1][q * 132 + c] +
                      Ul[2][q * 132 + c] + Ul[3][q * 132 + c];
        }
        if (tid < 16)
            rspart[(b * 32 + chunk) * 16 + tid] =
                rsw[0][tid] + rsw[1][tid] + rsw[2][tid] + rsw[3][tid];
    }
}

// ---------------------------------------------------------------------------
// Kernel 3 v4 (per iter): one row per block, 1024 threads (16 waves).
// 2 blocks/CU = 32 waves/CU. GEMV phases split outputs x K-slices across all
// 1024 threads with coalesced packed weights; partials via LDS red[1024].
// ---------------------------------------------------------------------------
__global__ __launch_bounds__(1024, 4) void k_tail(
    const float* __restrict__ Upart, const float* __restrict__ rspart,
    const float* __restrict__ hsrc, float* __restrict__ q_buf,
    const unsigned short* __restrict__ wihT, const unsigned short* __restrict__ whhT,
    const float* __restrict__ bih, const float* __restrict__ bhh,
    const float* __restrict__ ln2g, const float* __restrict__ ln2b,
    const unsigned short* __restrict__ w1T, const float* __restrict__ b1,
    const unsigned short* __restrict__ w2T, const float* __restrict__ b2,
    const float* __restrict__ lnqg, const float* __restrict__ lnqb,
    const float* __restrict__ wqTf, unsigned short* __restrict__ qn_g,
    float* __restrict__ out_q, int last)
{
    __shared__ __align__(16) float red[1024];
    __shared__ __align__(16) float u_l[128];
    __shared__ __align__(16) float h_l[128];
    __shared__ __align__(16) float y_l[128];
    __shared__ __align__(16) float z_l[128];
    __shared__ __align__(16) float g_l[768];
    __shared__ __align__(16) float h1_l[512];
    __shared__ float srs;
    const int tid = threadIdx.x;
    const int row = blockIdx.x;
    const int b = row >> 4, q = row & 15;

    // ---- Phase 0: Upart 8-way partial reduce; h load; rspart reduce ----
    {
        int c = tid & 127, h = tid >> 7;   // h in 0..7
        const float* up = Upart + (b * 32 + h * 4) * 2048 + q * 128 + c;
        float part = 0.f;
#pragma unroll
        for (int ch = 0; ch < 4; ch++) part += up[ch * 2048];
        red[tid] = part;
        if (tid < 128) h_l[tid] = hsrc[row * 128 + tid];
        if (tid >= 128 && tid < 160) {
            int t = tid - 128;
            float v = rspart[(b * 32 + t) * 16 + q];
            v += __shfl_xor(v, 1); v += __shfl_xor(v, 2); v += __shfl_xor(v, 4);
            v += __shfl_xor(v, 8); v += __shfl_xor(v, 16);
            if (t == 0) srs = v;
        }
    }
    __syncthreads();
    if (tid < 128) {
        float s = 0.f;
#pragma unroll
        for (int h = 0; h < 8; h++) s += red[tid + 128 * h];
        u_l[tid] = s / (srs + EPS_ATTN);
    }
    __syncthreads();
    // ---- GRU gates: 768 outputs, 1 per thread, coalesced packed W ----
    if (tid < 768) {
        int o = tid;
        const uint2* wp;
        const float* src;
        float bias;
        if (o < 384) { wp = (const uint2*)wihT + o; src = u_l; bias = bih[o]; }
        else         { wp = (const uint2*)whhT + (o - 384); src = h_l; bias = bhh[o - 384]; }
        float acc = 0.f;
#pragma unroll 4
        for (int g = 0; g < 32; g++) {
            uint2 w = wp[g * 384];
            float4 sv = *(const float4*)&src[g * 4];
            acc += blo(w.x) * sv.x + bhi(w.x) * sv.y
                 + blo(w.y) * sv.z + bhi(w.y) * sv.w;
        }
        g_l[o] = acc + bias;
    }
    __syncthreads();
    if (tid < 128) {
        int c = tid;
        float ir = g_l[c], iz = g_l[128 + c], in_ = g_l[256 + c];
        float hr = g_l[384 + c], hz = g_l[512 + c], hn = g_l[640 + c];
        float rr = 1.f / (1.f + expf(-(ir + hr)));
        float zz = 1.f / (1.f + expf(-(iz + hz)));
        float nn = tanhf(in_ + rr * hn);
        y_l[c] = (1.f - zz) * nn + zz * h_l[c];
    }
    __syncthreads();
    // ---- LN2: per-wave redundant stats ----
    {
        int l = tid & 63;
        float v0 = y_l[l], v1 = y_l[l + 64];
        float s = v0 + v1, ss = v0 * v0 + v1 * v1;
#pragma unroll
        for (int off = 1; off < 64; off <<= 1) {
            s += __shfl_xor(s, off);
            ss += __shfl_xor(ss, off);
        }
        float mean = s * (1.f / 128.f);
        float var = ss * (1.f / 128.f) - mean * mean;
        float rstd = rsqrtf(var + EPS_LN);
        if (tid < 128)
            z_l[tid] = (y_l[tid] - mean) * rstd * ln2g[tid] + ln2b[tid];
    }
    __syncthreads();
    // ---- FFN1 ----
    {
        int f = tid & 511, hh = tid >> 9;
        const uint2* wp = (const uint2*)w1T + f;
        float acc = 0.f;
#pragma unroll 4
        for (int j = 0; j < 16; j++) {
            int g = hh * 16 + j;
            uint2 w = wp[g * 512];
            float4 zv = *(const float4*)&z_l[g * 4];
            acc += blo(w.x) * zv.x + bhi(w.x) * zv.y
                 + blo(w.y) * zv.z + bhi(w.y) * zv.w;
        }
        red[tid] = acc;
    }
    __syncthreads();
    if (tid < 512)
        h1_l[tid] = fmaxf(red[tid] + red[tid + 512] + b1[tid], 0.f);
    __syncthreads();
    // ---- FFN2 ----
    {
        int c = tid & 127, h8 = tid >> 7;
        const uint2* wp = (const uint2*)w2T + c;
        float acc = 0.f;
#pragma unroll 4
        for (int j = 0; j < 16; j++) {
            int g = h8 * 16 + j;
            uint2 w = wp[g * 128];
            float4 hv = *(const float4*)&h1_l[g * 4];
            acc += blo(w.x) * hv.x + bhi(w.x) * hv.y
                 + blo(w.y) * hv.z + bhi(w.y) * hv.w;
        }
        red[tid] = acc;
    }
    __syncthreads();
    if (tid < 128) {
        float f2 = 0.f;
#pragma unroll
        for (int k = 0; k < 8; k++) f2 += red[tid + 128 * k];
        float qn = y_l[tid] + f2 + b2[tid];
        u_l[tid] = qn;
        q_buf[row * 128 + tid] = qn;
        if (last) out_q[row * 128 + tid] = qn;
    }
    if (last) return;
    __syncthreads();
    // ---- LN(q_new) ----
    {
        int l = tid & 63;
        float v0 = u_l[l], v1 = u_l[l + 64];
        float s = v0 + v1, ss = v0 * v0 + v1 * v1;
#pragma unroll
        for (int off = 1; off < 64; off <<= 1) {
            s += __shfl_xor(s, off);
            ss += __shfl_xor(ss, off);
        }
        float mean = s * (1.f / 128.f);
        float var = ss * (1.f / 128.f) - mean * mean;
        float rstd = rsqrtf(var + EPS_LN);
        if (tid < 128)
            z_l[tid] = (u_l[tid] - mean) * rstd * lnqg[tid] + lnqb[tid];
    }
    __syncthreads();
    // ---- qn_next = LN(q_new) @ Wq^T * scale ----
    {
        int c = tid & 127, h8 = tid >> 7;
        const float4* wp = (const float4*)wqTf + c;
        float acc = 0.f;
#pragma unroll
        for (int j = 0; j < 4; j++) {
            int g = h8 * 4 + j;
            float4 w = wp[g * 128];
            float4 zv = *(const float4*)&z_l[g * 4];
            acc += w.x * zv.x + w.y * zv.y + w.z * zv.z + w.w * zv.w;
        }
        red[tid] = acc;
    }
    __syncthreads();
    if (tid < 128) {
        float qa = 0.f;
#pragma unroll
        for (int k = 0; k < 8; k++) qa += red[tid + 128 * k];
        qn_g[row * 128 + tid] = f2b(qa * 0.08838834764831845f);
    }
}

// ---------------------------------------------------------------------------
extern "C" void kernel_launch(void* const* d_in, const int* in_sizes, int n_in,
                              void* d_out, int out_size, void* d_ws, size_t ws_size,
                              hipStream_t stream) {
    const float* inp     = (const float*)d_in[0];
    const float* query   = (const float*)d_in[1];
    const float* ln_kv_g = (const float*)d_in[2];
    const float* ln_kv_b = (const float*)d_in[3];
    const float* Wk      = (const float*)d_in[4];
    const float* Wv      = (const float*)d_in[5];
    const float* ln_q_g  = (const float*)d_in[6];
    const float* ln_q_b  = (const float*)d_in[7];
    const float* Wq      = (const float*)d_in[8];
    const float* gru_wih = (const float*)d_in[9];
    const float* gru_whh = (const float*)d_in[10];
    const float* gru_bih = (const float*)d_in[11];
    const float* gru_bhh = (const float*)d_in[12];
    const float* ln2_g   = (const float*)d_in[13];
    const float* ln2_b   = (const float*)d_in[14];
    const float* ffn_w1  = (const float*)d_in[15];
    const float* ffn_b1  = (const float*)d_in[16];
    const float* ffn_w2  = (const float*)d_in[17];
    const float* ffn_b2  = (const float*)d_in[18];

    char* ws = (char*)d_ws;
    unsigned short* Kbf    = (unsigned short*)ws;                  // 33554432
    unsigned short* Vt     = (unsigned short*)(ws + 33554432);     // 33554432
    float* q_buf           = (float*)(ws + 67108864);              // 262144
    float* Upart           = (float*)(ws + 67371008);              // 8388608
    float* rspart          = (float*)(ws + 75759616);              // 65536
    unsigned short* qn_g   = (unsigned short*)(ws + 75825152);     // 131072
    unsigned short* Wk_sw  = (unsigned short*)(ws + 75956224);     // 32768
    unsigned short* Wv_sw  = (unsigned short*)(ws + 75988992);     // 32768
    unsigned short* wihT   = (unsigned short*)(ws + 76021760);     // 98304
    unsigned short* whhT   = (unsigned short*)(ws + 76120064);     // 98304
    unsigned short* w1T    = (unsigned short*)(ws + 76218368);     // 131072
    unsigned short* w2T    = (unsigned short*)(ws + 76349440);     // 131072
    float* wqTf            = (float*)(ws + 76480512);              // 65536

    float* out_q  = (float*)d_out;
    float* out_a0 = out_q + B_ * N_ * C_;

    k_prep<<<dim3(304), dim3(256), 0, stream>>>(
        Wk, Wv, gru_wih, gru_whh, ffn_w1, ffn_w2,
        Wk_sw, Wv_sw, wihT, whhT, w1T, w2T,
        query, ln_q_g, ln_q_b, Wq, wqTf, qn_g);
    k_kvproj<<<dim3((B_ * HW_) / 128), dim3(512), 0, stream>>>(
        inp, ln_kv_g, ln_kv_b, Wk_sw, Wv_sw, Kbf, Vt);

    for (int it = 0; it < ITERS_; it++) {
        int last = (it == ITERS_ - 1) ? 1 : 0;
        const float* hsrc = (it == 0) ? query : q_buf;
        k_attn<<<dim3(32, B_), dim3(256), 0, stream>>>(
            qn_g, Kbf, Vt, Upart, rspart, out_a0, last);
        k_tail<<<dim3(B_ * N_), dim3(1024), 0, stream>>>(
            Upart, rspart, hsrc, q_buf, wihT, whhT, gru_bih, gru_bhh,
            ln2_g, ln2_b, w1T, ffn_b1, w2T, ffn_b2,
            ln_q_g, ln_q_b, wqTf, qn_g, out_q, last);
    }
}

// Round 6
// 282.814 us; speedup vs baseline: 1.4844x; 1.0150x over previous
//
#include <hip/hip_runtime.h>
#include <math.h>

#define B_ 32
#define HW_ 4096
#define N_ 16
#define C_ 128
#define F_ 512
#define ITERS_ 3
#define EPS_LN 1e-5f
#define EPS_ATTN 1e-5f

typedef __attribute__((ext_vector_type(8))) short short8;
typedef __attribute__((ext_vector_type(4))) float f32x4;

static __device__ __forceinline__ unsigned short f2b(float f) {
    union { float f; unsigned u; } v; v.f = f;
    unsigned r = v.u + 0x7fffu + ((v.u >> 16) & 1u);
    return (unsigned short)(r >> 16);
}
static __device__ __forceinline__ float blo(unsigned u) {
    union { unsigned u; float f; } v; v.u = u << 16; return v.f;
}
static __device__ __forceinline__ float bhi(unsigned u) {
    union { unsigned u; float f; } v; v.u = u & 0xffff0000u; return v.f;
}
// async global->LDS, 16B per lane; LDS dest is wave-uniform base + lane*16
static __device__ __forceinline__ void gload_lds16(const void* g, void* l) {
    __builtin_amdgcn_global_load_lds(
        (const __attribute__((address_space(1))) unsigned int*)g,
        (__attribute__((address_space(3))) unsigned int*)l, 16, 0, 0);
}

// ---------------------------------------------------------------------------
// One-time prep.
// Blocks 0..31:    Wk,Wv fp32->bf16 PRE-SWIZZLED into the kvproj LDS layout.
// Blocks 32..255:  transpose-packed bf16 of wih/whh/w1/w2 for k_tail.
// Blocks 256..287: qn_0 = (LN(query)*g+b) @ Wq^T * scale.
// Blocks 288..303: transpose-pack Wq (fp32) -> wqTf[g*128 + c] = Wq[c][4g..]
// ---------------------------------------------------------------------------
__global__ __launch_bounds__(256) void k_prep(
    const float* __restrict__ Wk, const float* __restrict__ Wv,
    const float* __restrict__ wih, const float* __restrict__ whh,
    const float* __restrict__ w1, const float* __restrict__ w2,
    unsigned short* __restrict__ Wk_sw, unsigned short* __restrict__ Wv_sw,
    unsigned short* __restrict__ wihT, unsigned short* __restrict__ whhT,
    unsigned short* __restrict__ w1T, unsigned short* __restrict__ w2T,
    const float* __restrict__ query, const float* __restrict__ lnqg,
    const float* __restrict__ lnqb, const float* __restrict__ Wq,
    float* __restrict__ wqTf, unsigned short* __restrict__ qn_g)
{
    __shared__ __align__(16) float xq[16 * 128];
    int tid = threadIdx.x;
    int blk = blockIdx.x;
    if (blk < 32) {
        int t = blk * 256 + tid;           // float4-group id, 0..8191
        const float* src; unsigned short* dst; int off;
        if (t < 4096) { src = Wk; dst = Wk_sw; off = t; }
        else          { src = Wv; dst = Wv_sw; off = t - 4096; }
        float4 a = ((const float4*)src)[off];
        uint2 p;
        p.x = (unsigned)f2b(a.x) | ((unsigned)f2b(a.y) << 16);
        p.y = (unsigned)f2b(a.z) | ((unsigned)f2b(a.w) << 16);
        int r = off >> 5;                  // row 0..127
        int j = off & 31;                  // 4-short group within row
        int cg = j >> 1, half = j & 1;     // 8-short col-group + half
        int dsw = r * 128 + (((cg ^ (r & 7)) << 3)) + (half << 2);
        *(uint2*)(dst + dsw) = p;
        return;
    }
    if (blk < 256) {
        const float* src; unsigned short* dst; int o, g, id, Cin;
        if (blk < 80) {         // wih: R=384, Cin=128
            id = (blk - 32) * 256 + tid;
            g = id / 384; o = id - g * 384;
            src = wih; dst = wihT; Cin = 128;
        } else if (blk < 128) { // whh: R=384
            id = (blk - 80) * 256 + tid;
            g = id / 384; o = id - g * 384;
            src = whh; dst = whhT; Cin = 128;
        } else if (blk < 192) { // w1: R=512, Cin=128
            id = (blk - 128) * 256 + tid;
            g = id >> 9; o = id & 511;
            src = w1; dst = w1T; Cin = 128;
        } else {                // w2: R=128, Cin=512
            id = (blk - 192) * 256 + tid;
            g = id >> 7; o = id & 127;
            src = w2; dst = w2T; Cin = 512;
        }
        float4 a = *(const float4*)(src + o * Cin + g * 4);
        uint2 p;
        p.x = (unsigned)f2b(a.x) | ((unsigned)f2b(a.y) << 16);
        p.y = (unsigned)f2b(a.z) | ((unsigned)f2b(a.w) << 16);
        *(uint2*)(dst + id * 4) = p;
        return;
    }
    if (blk >= 288) {
        int t = (blk - 288) * 256 + tid;   // 0..4095
        int c = t & 127, g = t >> 7;       // g 0..31
        float4 a = *(const float4*)(Wq + c * 128 + g * 4);
        ((float4*)wqTf)[g * 128 + c] = a;
        return;
    }
    int b = blk - 256;
    int n = tid >> 4, part = tid & 15;
    int row = b * 16 + n;
    const float4* x4 = (const float4*)(query + row * 128 + part * 8);
    float4 x0 = x4[0], x1 = x4[1];
    float s = x0.x + x0.y + x0.z + x0.w + x1.x + x1.y + x1.z + x1.w;
    float ss = x0.x * x0.x + x0.y * x0.y + x0.z * x0.z + x0.w * x0.w +
               x1.x * x1.x + x1.y * x1.y + x1.z * x1.z + x1.w * x1.w;
    s += __shfl_xor(s, 1); s += __shfl_xor(s, 2); s += __shfl_xor(s, 4); s += __shfl_xor(s, 8);
    ss += __shfl_xor(ss, 1); ss += __shfl_xor(ss, 2); ss += __shfl_xor(ss, 4); ss += __shfl_xor(ss, 8);
    float mean = s * (1.f / 128.f);
    float var = ss * (1.f / 128.f) - mean * mean;
    float rstd = rsqrtf(var + EPS_LN);
    const float4* g4 = (const float4*)(lnqg + part * 8);
    const float4* b4 = (const float4*)(lnqb + part * 8);
    float4 g0 = g4[0], g1 = g4[1], bb0 = b4[0], bb1 = b4[1];
    float4 o0, o1;
    o0.x = (x0.x - mean) * rstd * g0.x + bb0.x;
    o0.y = (x0.y - mean) * rstd * g0.y + bb0.y;
    o0.z = (x0.z - mean) * rstd * g0.z + bb0.z;
    o0.w = (x0.w - mean) * rstd * g0.w + bb0.w;
    o1.x = (x1.x - mean) * rstd * g1.x + bb1.x;
    o1.y = (x1.y - mean) * rstd * g1.y + bb1.y;
    o1.z = (x1.z - mean) * rstd * g1.z + bb1.z;
    o1.w = (x1.w - mean) * rstd * g1.w + bb1.w;
    float4* xrow = (float4*)&xq[n * 128];
    xrow[part * 2] = o0;
    xrow[part * 2 + 1] = o1;
    __syncthreads();
    float o[8] = {0.f, 0.f, 0.f, 0.f, 0.f, 0.f, 0.f, 0.f};
    const float4* xv4 = (const float4*)&xq[n * 128];
#pragma unroll 4
    for (int j = 0; j < 32; j++) {
        float4 xv = xv4[j];
#pragma unroll
        for (int i = 0; i < 8; i++) {
            float4 w = ((const float4*)(Wq + (part * 8 + i) * 128))[j];
            o[i] += w.x * xv.x + w.y * xv.y + w.z * xv.z + w.w * xv.w;
        }
    }
    const float scale = 0.08838834764831845f;
#pragma unroll
    for (int i = 0; i < 8; i++)
        qn_g[row * 128 + part * 8 + i] = f2b(o[i] * scale);
}

// ---------------------------------------------------------------------------
// Kernel 1 (round-5 proven, ~50us): 128 rows/block, 512 threads, async
// pre-swizzled W staging via global_load_lds.
// ---------------------------------------------------------------------------
__global__ __launch_bounds__(512, 4) void k_kvproj(
    const float* __restrict__ inp, const float* __restrict__ lng,
    const float* __restrict__ lnb, const unsigned short* __restrict__ Wk_sw,
    const unsigned short* __restrict__ Wv_sw, unsigned short* __restrict__ Kbf,
    unsigned short* __restrict__ Vt)
{
    __shared__ __align__(16) unsigned short W_lds[128 * 128];  // 32 KB
    __shared__ __align__(16) unsigned short T_lds[128 * 132];  // 33.8 KB
    const int tid = threadIdx.x;
    const int wave = tid >> 6, lane = tid & 63;
    const int l15 = lane & 15, q4 = lane >> 4;
    const int kof = q4 * 8;
    const int tile0 = blockIdx.x * 128;
    const int b = tile0 >> 12;
    const int hwbase = tile0 & (HW_ - 1);

    // ---- issue Wk -> LDS async ----
    {
        const char* gw = (const char*)Wk_sw + wave * 4096 + lane * 16;
        char* lw = (char*)W_lds + wave * 4096;
#pragma unroll
        for (int j = 0; j < 4; j++)
            gload_lds16(gw + j * 1024, lw + j * 1024);
    }

    // ---- in-register LN ----
    float x[4][8];
    {
        const float* rowp = inp + (tile0 + (wave << 4) + l15) * C_;
        float s = 0.f, ss = 0.f;
#pragma unroll
        for (int ks = 0; ks < 4; ks++) {
#pragma unroll
            for (int h = 0; h < 2; h++) {
                float4 v = *(const float4*)(rowp + ks * 32 + kof + h * 4);
                x[ks][h * 4 + 0] = v.x; x[ks][h * 4 + 1] = v.y;
                x[ks][h * 4 + 2] = v.z; x[ks][h * 4 + 3] = v.w;
                s += v.x + v.y + v.z + v.w;
                ss += v.x * v.x + v.y * v.y + v.z * v.z + v.w * v.w;
            }
        }
        s += __shfl_xor(s, 16);  s += __shfl_xor(s, 32);
        ss += __shfl_xor(ss, 16); ss += __shfl_xor(ss, 32);
        float mean = s * (1.f / 128.f);
        float var = ss * (1.f / 128.f) - mean * mean;
        float rstd = rsqrtf(var + EPS_LN);
#pragma unroll
        for (int ks = 0; ks < 4; ks++) {
#pragma unroll
            for (int h = 0; h < 2; h++) {
                float4 g = *(const float4*)(lng + ks * 32 + kof + h * 4);
                float4 bb = *(const float4*)(lnb + ks * 32 + kof + h * 4);
                x[ks][h * 4 + 0] = (x[ks][h * 4 + 0] - mean) * rstd * g.x + bb.x;
                x[ks][h * 4 + 1] = (x[ks][h * 4 + 1] - mean) * rstd * g.y + bb.y;
                x[ks][h * 4 + 2] = (x[ks][h * 4 + 2] - mean) * rstd * g.z + bb.z;
                x[ks][h * 4 + 3] = (x[ks][h * 4 + 3] - mean) * rstd * g.w + bb.w;
            }
        }
    }
    short8 af[4];
#pragma unroll
    for (int ks = 0; ks < 4; ks++) {
        union { short8 s8; unsigned u[4]; } p;
#pragma unroll
        for (int j = 0; j < 4; j++)
            p.u[j] = (unsigned)f2b(x[ks][2 * j]) | ((unsigned)f2b(x[ks][2 * j + 1]) << 16);
        af[ks] = p.s8;
    }

    __syncthreads();   // [1] Wk in LDS

    // ---- K phase ----
    f32x4 acc[8];
#pragma unroll
    for (int nt = 0; nt < 8; nt++) {
        acc[nt] = (f32x4){0.f, 0.f, 0.f, 0.f};
#pragma unroll
        for (int ks = 0; ks < 4; ks++) {
            short8 bf = *(const short8*)&W_lds[(nt * 16 + l15) * 128 + ((ks * 4 + q4) ^ (l15 & 7)) * 8];
            acc[nt] = __builtin_amdgcn_mfma_f32_16x16x32_bf16(af[ks], bf, acc[nt], 0, 0, 0);
        }
    }
#pragma unroll
    for (int nt = 0; nt < 8; nt++) {
        int c = nt * 16 + l15;
#pragma unroll
        for (int i = 0; i < 4; i++)
            T_lds[((wave << 4) + (q4 << 2) + i) * 132 + c] = f2b(acc[nt][i]);
    }
    __syncthreads();   // [2]

    {
        int row = tid >> 2, part = tid & 3;
        uint4* dst = (uint4*)&Kbf[(b * HW_ + hwbase + row) * C_ + part * 32];
#pragma unroll
        for (int j = 0; j < 4; j++)
            dst[j] = *(const uint4*)&T_lds[row * 132 + part * 32 + j * 8];
    }
    // ---- issue Wv -> LDS async ----
    {
        const char* gw = (const char*)Wv_sw + wave * 4096 + lane * 16;
        char* lw = (char*)W_lds + wave * 4096;
#pragma unroll
        for (int j = 0; j < 4; j++)
            gload_lds16(gw + j * 1024, lw + j * 1024);
    }
    __syncthreads();   // [3]

    // ---- V phase ----
#pragma unroll
    for (int nt = 0; nt < 8; nt++) {
        acc[nt] = (f32x4){0.f, 0.f, 0.f, 0.f};
#pragma unroll
        for (int ks = 0; ks < 4; ks++) {
            short8 bf = *(const short8*)&W_lds[(nt * 16 + l15) * 128 + ((ks * 4 + q4) ^ (l15 & 7)) * 8];
            acc[nt] = __builtin_amdgcn_mfma_f32_16x16x32_bf16(af[ks], bf, acc[nt], 0, 0, 0);
        }
    }
#pragma unroll
    for (int nt = 0; nt < 8; nt++) {
        int c = nt * 16 + l15;
#pragma unroll
        for (int i = 0; i < 4; i++)
            T_lds[c * 132 + (wave << 4) + (q4 << 2) + i] = f2b(acc[nt][i]);
    }
    __syncthreads();   // [4]

    {
        int c = tid >> 2, part = tid & 3;
        uint4* dst = (uint4*)&Vt[(b * C_ + c) * HW_ + hwbase + part * 32];
#pragma unroll
        for (int j = 0; j < 4; j++)
            dst[j] = *(const uint4*)&T_lds[c * 132 + part * 32 + j * 8];
    }
}

// ---------------------------------------------------------------------------
// Kernel 2 (per iter): 256-thread blocks (4 waves), grid (32, B).
// ---------------------------------------------------------------------------
__global__ __launch_bounds__(256) void k_attn(
    const unsigned short* __restrict__ qn_g, const unsigned short* __restrict__ Kbf,
    const unsigned short* __restrict__ Vt, float* __restrict__ Upart,
    float* __restrict__ rspart, float* __restrict__ a0_out, int last)
{
    __shared__ __align__(16) float Ul[4][16 * 132];          // 33.8 KB
    __shared__ __align__(16) unsigned short Pb[4][16 * 40];  // 5.1 KB
    __shared__ float rsw[4][16];
    const int b = blockIdx.y, chunk = blockIdx.x;
    const int tid = threadIdx.x;
    const int wave = tid >> 6, lane = tid & 63;
    const int l15 = lane & 15, q4 = lane >> 4;
    const int kof = q4 * 8;
    const int hwb = chunk * 128 + wave * 32;

    short8 aq[4];
#pragma unroll
    for (int ks = 0; ks < 4; ks++)
        aq[ks] = *(const short8*)&qn_g[(b * 16 + l15) * 128 + ks * 32 + kof];
    short8 av[8];
#pragma unroll
    for (int ct = 0; ct < 8; ct++)
        av[ct] = *(const short8*)&Vt[(b * C_ + ct * 16 + l15) * HW_ + hwb + kof];

    unsigned short* Pw = &Pb[wave][0];
    float rs[4] = {0.f, 0.f, 0.f, 0.f};
#pragma unroll
    for (int s = 0; s < 2; s++) {
        int hwt = hwb + s * 16;
        f32x4 sa = {0.f, 0.f, 0.f, 0.f};
#pragma unroll
        for (int ks = 0; ks < 4; ks++) {
            short8 bk = *(const short8*)&Kbf[(b * HW_ + hwt + l15) * C_ + ks * 32 + kof];
            sa = __builtin_amdgcn_mfma_f32_16x16x32_bf16(aq[ks], bk, sa, 0, 0, 0);
        }
        float mx = fmaxf(fmaxf(sa[0], sa[1]), fmaxf(sa[2], sa[3]));
        mx = fmaxf(mx, __shfl_xor(mx, 16));
        mx = fmaxf(mx, __shfl_xor(mx, 32));
        float e[4]; float ssum = 0.f;
#pragma unroll
        for (int i = 0; i < 4; i++) { e[i] = __expf(sa[i] - mx); ssum += e[i]; }
        ssum += __shfl_xor(ssum, 16);
        ssum += __shfl_xor(ssum, 32);
        float inv = 1.f / ssum;
#pragma unroll
        for (int i = 0; i < 4; i++) {
            float a0v = e[i] * inv;
            rs[i] += a0v;
            if (last) a0_out[(b * 16 + q4 * 4 + i) * HW_ + hwt + l15] = a0v;
            Pw[(q4 * 4 + i) * 40 + s * 16 + l15] = f2b(a0v);
        }
    }
#pragma unroll
    for (int i = 0; i < 4; i++) {
        rs[i] += __shfl_xor(rs[i], 1);
        rs[i] += __shfl_xor(rs[i], 2);
        rs[i] += __shfl_xor(rs[i], 4);
        rs[i] += __shfl_xor(rs[i], 8);
    }
    if (l15 == 0) {
#pragma unroll
        for (int i = 0; i < 4; i++) rsw[wave][q4 * 4 + i] = rs[i];
    }
    short8 bp = *(const short8*)&Pw[l15 * 40 + kof];
#pragma unroll
    for (int ct = 0; ct < 8; ct++) {
        f32x4 ua = __builtin_amdgcn_mfma_f32_16x16x32_bf16(av[ct], bp, (f32x4){0.f, 0.f, 0.f, 0.f}, 0, 0, 0);
        *(f32x4*)&Ul[wave][l15 * 132 + ct * 16 + (q4 << 2)] = ua;
    }
    __syncthreads();
    {
        float* up = Upart + (b * 32 + chunk) * 2048;
#pragma unroll
        for (int k = 0; k < 8; k++) {
            int idx = tid + k * 256;          // idx = q*128 + c
            int q = idx >> 7, c = idx & 127;
            up[idx] = Ul[0][q * 132 + c] + Ul[1][q * 132 + c] +
                      Ul[2][q * 132 + c] + Ul[3][q * 132 + c];
        }
        if (tid < 16)
            rspart[(b * 32 + chunk) * 16 + tid] =
                rsw[0][tid] + rsw[1][tid] + rsw[2][tid] + rsw[3][tid];
    }
}

// ---------------------------------------------------------------------------
// Kernel 3 v5 (per iter): TWO rows per block, 512 threads, grid 256.
// Mechanism (r5 post-mortem): v4's cost = per-block weight re-streaming from
// L2 (512 blocks x 512KB = 262MB/iter) + 12 serial latency phases per row.
// v5 loads each weight once and FMAs it against BOTH rows' activations:
// L2 weight traffic halved, barriers/row halved (10 for 2 rows).
// ---------------------------------------------------------------------------
__global__ __launch_bounds__(512) void k_tail(
    const float* __restrict__ Upart, const float* __restrict__ rspart,
    const float* __restrict__ hsrc, float* __restrict__ q_buf,
    const unsigned short* __restrict__ wihT, const unsigned short* __restrict__ whhT,
    const float* __restrict__ bih, const float* __restrict__ bhh,
    const float* __restrict__ ln2g, const float* __restrict__ ln2b,
    const unsigned short* __restrict__ w1T, const float* __restrict__ b1,
    const unsigned short* __restrict__ w2T, const float* __restrict__ b2,
    const float* __restrict__ lnqg, const float* __restrict__ lnqb,
    const float* __restrict__ wqTf, unsigned short* __restrict__ qn_g,
    float* __restrict__ out_q, int last)
{
    __shared__ __align__(16) float red0[512], red1[512];
    __shared__ __align__(16) float u0_l[128], u1_l[128];
    __shared__ __align__(16) float h0_l[128], h1_l[128];
    __shared__ __align__(16) float y0_l[128], y1_l[128];
    __shared__ __align__(16) float z0_l[128], z1_l[128];
    __shared__ __align__(16) float g0_l[768], g1_l[768];
    __shared__ __align__(16) float f0_l[512], f1_l[512];
    __shared__ float srs0, srs1;
    const int tid = threadIdx.x;
    const int row0 = blockIdx.x * 2, row1 = row0 + 1;
    const int b = row0 >> 4, q0 = row0 & 15;

    // ---- Phase 0: Upart partial reduce (both rows); h loads; rspart ----
    {
        int c = tid & 127, h = tid >> 7;   // h in 0..3, 8 chunks each
        const float* upA = Upart + (b * 32 + h * 8) * 2048 + q0 * 128 + c;
        float a = 0.f, bv = 0.f;
#pragma unroll
        for (int ch = 0; ch < 8; ch++) {
            a  += upA[ch * 2048];
            bv += upA[ch * 2048 + 128];    // q1 = q0+1
        }
        red0[tid] = a; red1[tid] = bv;
        if (tid < 128) h0_l[tid] = hsrc[row0 * 128 + tid];
        else if (tid < 256) h1_l[tid - 128] = hsrc[row1 * 128 + (tid - 128)];
        if (tid >= 256 && tid < 288) {
            int t = tid - 256;
            float v = rspart[(b * 32 + t) * 16 + q0];
            v += __shfl_xor(v, 1); v += __shfl_xor(v, 2); v += __shfl_xor(v, 4);
            v += __shfl_xor(v, 8); v += __shfl_xor(v, 16);
            if (t == 0) srs0 = v;
        }
        if (tid >= 320 && tid < 352) {
            int t = tid - 320;
            float v = rspart[(b * 32 + t) * 16 + q0 + 1];
            v += __shfl_xor(v, 1); v += __shfl_xor(v, 2); v += __shfl_xor(v, 4);
            v += __shfl_xor(v, 8); v += __shfl_xor(v, 16);
            if (t == 0) srs1 = v;
        }
    }
    __syncthreads();
    if (tid < 128) {
        float s = red0[tid] + red0[tid + 128] + red0[tid + 256] + red0[tid + 384];
        u0_l[tid] = s / (srs0 + EPS_ATTN);
    } else if (tid < 256) {
        int c = tid - 128;
        float s = red1[c] + red1[c + 128] + red1[c + 256] + red1[c + 384];
        u1_l[c] = s / (srs1 + EPS_ATTN);
    }
    __syncthreads();
    // ---- GRU gates: 768 outputs x 2 rows; weight loaded once per output ----
    {
        int o = tid;
        const uint2* wp; const float *sA, *sB; float bias;
        if (o < 384) { wp = (const uint2*)wihT + o; sA = u0_l; sB = u1_l; bias = bih[o]; }
        else         { wp = (const uint2*)whhT + (o - 384); sA = h0_l; sB = h1_l; bias = bhh[o - 384]; }
        float fa = 0.f, fb = 0.f;
#pragma unroll 4
        for (int g = 0; g < 32; g++) {
            uint2 w = wp[g * 384];
            float4 a4 = *(const float4*)&sA[g * 4];
            float4 b4 = *(const float4*)&sB[g * 4];
            float w0 = blo(w.x), w1v = bhi(w.x), w2v = blo(w.y), w3 = bhi(w.y);
            fa += w0 * a4.x + w1v * a4.y + w2v * a4.z + w3 * a4.w;
            fb += w0 * b4.x + w1v * b4.y + w2v * b4.z + w3 * b4.w;
        }
        g0_l[o] = fa + bias; g1_l[o] = fb + bias;
        if (tid < 256) {
            int o2 = tid + 512;            // 512..767 -> whh rows 128..383
            const uint2* wp2 = (const uint2*)whhT + (o2 - 384);
            float fa2 = 0.f, fb2 = 0.f;
#pragma unroll 4
            for (int g = 0; g < 32; g++) {
                uint2 w = wp2[g * 384];
                float4 a4 = *(const float4*)&h0_l[g * 4];
                float4 b4 = *(const float4*)&h1_l[g * 4];
                float w0 = blo(w.x), w1v = bhi(w.x), w2v = blo(w.y), w3 = bhi(w.y);
                fa2 += w0 * a4.x + w1v * a4.y + w2v * a4.z + w3 * a4.w;
                fb2 += w0 * b4.x + w1v * b4.y + w2v * b4.z + w3 * b4.w;
            }
            float bias2 = bhh[o2 - 384];
            g0_l[o2] = fa2 + bias2; g1_l[o2] = fb2 + bias2;
        }
    }
    __syncthreads();
    // ---- GRU elementwise: 2 rows x 128 channels ----
    if (tid < 256) {
        int c = tid & 127, r = tid >> 7;
        const float* gl = r ? g1_l : g0_l;
        const float* hl = r ? h1_l : h0_l;
        float* yl = r ? y1_l : y0_l;
        float ir = gl[c], iz = gl[128 + c], in_ = gl[256 + c];
        float hr = gl[384 + c], hz = gl[512 + c], hn = gl[640 + c];
        float rr = 1.f / (1.f + expf(-(ir + hr)));
        float zz = 1.f / (1.f + expf(-(iz + hz)));
        float nn = tanhf(in_ + rr * hn);
        yl[c] = (1.f - zz) * nn + zz * hl[c];
    }
    __syncthreads();
    // ---- LN2: waves 0-3 handle row0, waves 4-7 row1 (redundant stats) ----
    {
        int r = tid >> 8;
        const float* yl = r ? y1_l : y0_l;
        int l = tid & 63;
        float v0 = yl[l], v1 = yl[l + 64];
        float s = v0 + v1, ss = v0 * v0 + v1 * v1;
#pragma unroll
        for (int off = 1; off < 64; off <<= 1) {
            s += __shfl_xor(s, off);
            ss += __shfl_xor(ss, off);
        }
        float mean = s * (1.f / 128.f);
        float var = ss * (1.f / 128.f) - mean * mean;
        float rstd = rsqrtf(var + EPS_LN);
        int c = tid & 255;
        if (c < 128) {
            float* zl = r ? z1_l : z0_l;
            zl[c] = (yl[c] - mean) * rstd * ln2g[c] + ln2b[c];
        }
    }
    __syncthreads();
    // ---- FFN1: 512 outputs, full K dot, both rows per weight load ----
    {
        const uint2* wp = (const uint2*)w1T + tid;
        float fa = 0.f, fb = 0.f;
#pragma unroll 4
        for (int g = 0; g < 32; g++) {
            uint2 w = wp[g * 512];
            float4 za = *(const float4*)&z0_l[g * 4];
            float4 zb = *(const float4*)&z1_l[g * 4];
            float w0 = blo(w.x), w1v = bhi(w.x), w2v = blo(w.y), w3 = bhi(w.y);
            fa += w0 * za.x + w1v * za.y + w2v * za.z + w3 * za.w;
            fb += w0 * zb.x + w1v * zb.y + w2v * zb.z + w3 * zb.w;
        }
        float bb = b1[tid];
        f0_l[tid] = fmaxf(fa + bb, 0.f);
        f1_l[tid] = fmaxf(fb + bb, 0.f);
    }
    __syncthreads();
    // ---- FFN2: 128 outputs x 4 K-groups, both rows ----
    {
        int c = tid & 127, k4 = tid >> 7;
        const uint2* wp = (const uint2*)w2T + c;
        float fa = 0.f, fb = 0.f;
#pragma unroll 4
        for (int j = 0; j < 32; j++) {
            int g = k4 * 32 + j;
            uint2 w = wp[g * 128];
            float4 ha = *(const float4*)&f0_l[g * 4];
            float4 hb = *(const float4*)&f1_l[g * 4];
            float w0 = blo(w.x), w1v = bhi(w.x), w2v = blo(w.y), w3 = bhi(w.y);
            fa += w0 * ha.x + w1v * ha.y + w2v * ha.z + w3 * ha.w;
            fb += w0 * hb.x + w1v * hb.y + w2v * hb.z + w3 * hb.w;
        }
        red0[tid] = fa; red1[tid] = fb;
    }
    __syncthreads();
    if (tid < 128) {
        float f2 = red0[tid] + red0[tid + 128] + red0[tid + 256] + red0[tid + 384];
        float qn = y0_l[tid] + f2 + b2[tid];
        u0_l[tid] = qn;
        q_buf[row0 * 128 + tid] = qn;
        if (last) out_q[row0 * 128 + tid] = qn;
    } else if (tid < 256) {
        int c = tid - 128;
        float f2 = red1[c] + red1[c + 128] + red1[c + 256] + red1[c + 384];
        float qn = y1_l[c] + f2 + b2[c];
        u1_l[c] = qn;
        q_buf[row1 * 128 + c] = qn;
        if (last) out_q[row1 * 128 + c] = qn;
    }
    if (last) return;
    __syncthreads();
    // ---- LN(q_new): dual-row redundant stats ----
    {
        int r = tid >> 8;
        const float* yl = r ? u1_l : u0_l;
        int l = tid & 63;
        float v0 = yl[l], v1 = yl[l + 64];
        float s = v0 + v1, ss = v0 * v0 + v1 * v1;
#pragma unroll
        for (int off = 1; off < 64; off <<= 1) {
            s += __shfl_xor(s, off);
            ss += __shfl_xor(ss, off);
        }
        float mean = s * (1.f / 128.f);
        float var = ss * (1.f / 128.f) - mean * mean;
        float rstd = rsqrtf(var + EPS_LN);
        int c = tid & 255;
        if (c < 128) {
            float* zl = r ? z1_l : z0_l;
            zl[c] = (yl[c] - mean) * rstd * lnqg[c] + lnqb[c];
        }
    }
    __syncthreads();
    // ---- qn_next = LN(q_new) @ Wq^T * scale (fp32 packed, both rows) ----
    {
        int c = tid & 127, k4 = tid >> 7;
        const float4* wp = (const float4*)wqTf + c;
        float fa = 0.f, fb = 0.f;
#pragma unroll
        for (int j = 0; j < 8; j++) {
            int g = k4 * 8 + j;
            float4 w = wp[g * 128];
            float4 za = *(const float4*)&z0_l[g * 4];
            float4 zb = *(const float4*)&z1_l[g * 4];
            fa += w.x * za.x + w.y * za.y + w.z * za.z + w.w * za.w;
            fb += w.x * zb.x + w.y * zb.y + w.z * zb.z + w.w * zb.w;
        }
        red0[tid] = fa; red1[tid] = fb;
    }
    __syncthreads();
    if (tid < 128) {
        float qa = red0[tid] + red0[tid + 128] + red0[tid + 256] + red0[tid + 384];
        qn_g[row0 * 128 + tid] = f2b(qa * 0.08838834764831845f);
    } else if (tid < 256) {
        int c = tid - 128;
        float qa = red1[c] + red1[c + 128] + red1[c + 256] + red1[c + 384];
        qn_g[row1 * 128 + c] = f2b(qa * 0.08838834764831845f);
    }
}

// ---------------------------------------------------------------------------
extern "C" void kernel_launch(void* const* d_in, const int* in_sizes, int n_in,
                              void* d_out, int out_size, void* d_ws, size_t ws_size,
                              hipStream_t stream) {
    const float* inp     = (const float*)d_in[0];
    const float* query   = (const float*)d_in[1];
    const float* ln_kv_g = (const float*)d_in[2];
    const float* ln_kv_b = (const float*)d_in[3];
    const float* Wk      = (const float*)d_in[4];
    const float* Wv      = (const float*)d_in[5];
    const float* ln_q_g  = (const float*)d_in[6];
    const float* ln_q_b  = (const float*)d_in[7];
    const float* Wq      = (const float*)d_in[8];
    const float* gru_wih = (const float*)d_in[9];
    const float* gru_whh = (const float*)d_in[10];
    const float* gru_bih = (const float*)d_in[11];
    const float* gru_bhh = (const float*)d_in[12];
    const float* ln2_g   = (const float*)d_in[13];
    const float* ln2_b   = (const float*)d_in[14];
    const float* ffn_w1  = (const float*)d_in[15];
    const float* ffn_b1  = (const float*)d_in[16];
    const float* ffn_w2  = (const float*)d_in[17];
    const float* ffn_b2  = (const float*)d_in[18];

    char* ws = (char*)d_ws;
    unsigned short* Kbf    = (unsigned short*)ws;                  // 33554432
    unsigned short* Vt     = (unsigned short*)(ws + 33554432);     // 33554432
    float* q_buf           = (float*)(ws + 67108864);              // 262144
    float* Upart           = (float*)(ws + 67371008);              // 8388608
    float* rspart          = (float*)(ws + 75759616);              // 65536
    unsigned short* qn_g   = (unsigned short*)(ws + 75825152);     // 131072
    unsigned short* Wk_sw  = (unsigned short*)(ws + 75956224);     // 32768
    unsigned short* Wv_sw  = (unsigned short*)(ws + 75988992);     // 32768
    unsigned short* wihT   = (unsigned short*)(ws + 76021760);     // 98304
    unsigned short* whhT   = (unsigned short*)(ws + 76120064);     // 98304
    unsigned short* w1T    = (unsigned short*)(ws + 76218368);     // 131072
    unsigned short* w2T    = (unsigned short*)(ws + 76349440);     // 131072
    float* wqTf            = (float*)(ws + 76480512);              // 65536

    float* out_q  = (float*)d_out;
    float* out_a0 = out_q + B_ * N_ * C_;

    k_prep<<<dim3(304), dim3(256), 0, stream>>>(
        Wk, Wv, gru_wih, gru_whh, ffn_w1, ffn_w2,
        Wk_sw, Wv_sw, wihT, whhT, w1T, w2T,
        query, ln_q_g, ln_q_b, Wq, wqTf, qn_g);
    k_kvproj<<<dim3((B_ * HW_) / 128), dim3(512), 0, stream>>>(
        inp, ln_kv_g, ln_kv_b, Wk_sw, Wv_sw, Kbf, Vt);

    for (int it = 0; it < ITERS_; it++) {
        int last = (it == ITERS_ - 1) ? 1 : 0;
        const float* hsrc = (it == 0) ? query : q_buf;
        k_attn<<<dim3(32, B_), dim3(256), 0, stream>>>(
            qn_g, Kbf, Vt, Upart, rspart, out_a0, last);
        k_tail<<<dim3((B_ * N_) / 2), dim3(512), 0, stream>>>(
            Upart, rspart, hsrc, q_buf, wihT, whhT, gru_bih, gru_bhh,
            ln2_g, ln2_b, w1T, ffn_b1, w2T, ffn_b2,
            ln_q_g, ln_q_b, wqTf, qn_g, out_q, last);
    }
}

// Round 7
// 281.233 us; speedup vs baseline: 1.4928x; 1.0056x over previous
//
#include <hip/hip_runtime.h>
#include <math.h>

#define B_ 32
#define HW_ 4096
#define N_ 16
#define C_ 128
#define F_ 512
#define ITERS_ 3
#define EPS_LN 1e-5f
#define EPS_ATTN 1e-5f

typedef __attribute__((ext_vector_type(8))) short short8;
typedef __attribute__((ext_vector_type(4))) float f32x4;

static __device__ __forceinline__ unsigned short f2b(float f) {
    union { float f; unsigned u; } v; v.f = f;
    unsigned r = v.u + 0x7fffu + ((v.u >> 16) & 1u);
    return (unsigned short)(r >> 16);
}
static __device__ __forceinline__ float blo(unsigned u) {
    union { unsigned u; float f; } v; v.u = u << 16; return v.f;
}
static __device__ __forceinline__ float bhi(unsigned u) {
    union { unsigned u; float f; } v; v.u = u & 0xffff0000u; return v.f;
}
// async global->LDS, 16B per lane; LDS dest is wave-uniform base + lane*16
static __device__ __forceinline__ void gload_lds16(const void* g, void* l) {
    __builtin_amdgcn_global_load_lds(
        (const __attribute__((address_space(1))) unsigned int*)g,
        (__attribute__((address_space(3))) unsigned int*)l, 16, 0, 0);
}

// ---------------------------------------------------------------------------
// One-time prep.
// Blocks 0..31:    Wk,Wv fp32->bf16 PRE-SWIZZLED into the kvproj LDS layout.
// Blocks 32..255:  transpose-packed bf16 of wih/whh/w1/w2 for k_tail.
// Blocks 256..287: qn_0 = (LN(query)*g+b) @ Wq^T * scale.
// Blocks 288..303: transpose-pack Wq (fp32) -> wqTf[g*128 + c] = Wq[c][4g..]
// ---------------------------------------------------------------------------
__global__ __launch_bounds__(256) void k_prep(
    const float* __restrict__ Wk, const float* __restrict__ Wv,
    const float* __restrict__ wih, const float* __restrict__ whh,
    const float* __restrict__ w1, const float* __restrict__ w2,
    unsigned short* __restrict__ Wk_sw, unsigned short* __restrict__ Wv_sw,
    unsigned short* __restrict__ wihT, unsigned short* __restrict__ whhT,
    unsigned short* __restrict__ w1T, unsigned short* __restrict__ w2T,
    const float* __restrict__ query, const float* __restrict__ lnqg,
    const float* __restrict__ lnqb, const float* __restrict__ Wq,
    float* __restrict__ wqTf, unsigned short* __restrict__ qn_g)
{
    __shared__ __align__(16) float xq[16 * 128];
    int tid = threadIdx.x;
    int blk = blockIdx.x;
    if (blk < 32) {
        int t = blk * 256 + tid;           // float4-group id, 0..8191
        const float* src; unsigned short* dst; int off;
        if (t < 4096) { src = Wk; dst = Wk_sw; off = t; }
        else          { src = Wv; dst = Wv_sw; off = t - 4096; }
        float4 a = ((const float4*)src)[off];
        uint2 p;
        p.x = (unsigned)f2b(a.x) | ((unsigned)f2b(a.y) << 16);
        p.y = (unsigned)f2b(a.z) | ((unsigned)f2b(a.w) << 16);
        int r = off >> 5;                  // row 0..127
        int j = off & 31;                  // 4-short group within row
        int cg = j >> 1, half = j & 1;     // 8-short col-group + half
        int dsw = r * 128 + (((cg ^ (r & 7)) << 3)) + (half << 2);
        *(uint2*)(dst + dsw) = p;
        return;
    }
    if (blk < 256) {
        const float* src; unsigned short* dst; int o, g, id, Cin;
        if (blk < 80) {         // wih: R=384, Cin=128
            id = (blk - 32) * 256 + tid;
            g = id / 384; o = id - g * 384;
            src = wih; dst = wihT; Cin = 128;
        } else if (blk < 128) { // whh: R=384
            id = (blk - 80) * 256 + tid;
            g = id / 384; o = id - g * 384;
            src = whh; dst = whhT; Cin = 128;
        } else if (blk < 192) { // w1: R=512, Cin=128
            id = (blk - 128) * 256 + tid;
            g = id >> 9; o = id & 511;
            src = w1; dst = w1T; Cin = 128;
        } else {                // w2: R=128, Cin=512
            id = (blk - 192) * 256 + tid;
            g = id >> 7; o = id & 127;
            src = w2; dst = w2T; Cin = 512;
        }
        float4 a = *(const float4*)(src + o * Cin + g * 4);
        uint2 p;
        p.x = (unsigned)f2b(a.x) | ((unsigned)f2b(a.y) << 16);
        p.y = (unsigned)f2b(a.z) | ((unsigned)f2b(a.w) << 16);
        *(uint2*)(dst + id * 4) = p;
        return;
    }
    if (blk >= 288) {
        int t = (blk - 288) * 256 + tid;   // 0..4095
        int c = t & 127, g = t >> 7;       // g 0..31
        float4 a = *(const float4*)(Wq + c * 128 + g * 4);
        ((float4*)wqTf)[g * 128 + c] = a;
        return;
    }
    int b = blk - 256;
    int n = tid >> 4, part = tid & 15;
    int row = b * 16 + n;
    const float4* x4 = (const float4*)(query + row * 128 + part * 8);
    float4 x0 = x4[0], x1 = x4[1];
    float s = x0.x + x0.y + x0.z + x0.w + x1.x + x1.y + x1.z + x1.w;
    float ss = x0.x * x0.x + x0.y * x0.y + x0.z * x0.z + x0.w * x0.w +
               x1.x * x1.x + x1.y * x1.y + x1.z * x1.z + x1.w * x1.w;
    s += __shfl_xor(s, 1); s += __shfl_xor(s, 2); s += __shfl_xor(s, 4); s += __shfl_xor(s, 8);
    ss += __shfl_xor(ss, 1); ss += __shfl_xor(ss, 2); ss += __shfl_xor(ss, 4); ss += __shfl_xor(ss, 8);
    float mean = s * (1.f / 128.f);
    float var = ss * (1.f / 128.f) - mean * mean;
    float rstd = rsqrtf(var + EPS_LN);
    const float4* g4 = (const float4*)(lnqg + part * 8);
    const float4* b4 = (const float4*)(lnqb + part * 8);
    float4 g0 = g4[0], g1 = g4[1], bb0 = b4[0], bb1 = b4[1];
    float4 o0, o1;
    o0.x = (x0.x - mean) * rstd * g0.x + bb0.x;
    o0.y = (x0.y - mean) * rstd * g0.y + bb0.y;
    o0.z = (x0.z - mean) * rstd * g0.z + bb0.z;
    o0.w = (x0.w - mean) * rstd * g0.w + bb0.w;
    o1.x = (x1.x - mean) * rstd * g1.x + bb1.x;
    o1.y = (x1.y - mean) * rstd * g1.y + bb1.y;
    o1.z = (x1.z - mean) * rstd * g1.z + bb1.z;
    o1.w = (x1.w - mean) * rstd * g1.w + bb1.w;
    float4* xrow = (float4*)&xq[n * 128];
    xrow[part * 2] = o0;
    xrow[part * 2 + 1] = o1;
    __syncthreads();
    float o[8] = {0.f, 0.f, 0.f, 0.f, 0.f, 0.f, 0.f, 0.f};
    const float4* xv4 = (const float4*)&xq[n * 128];
#pragma unroll 4
    for (int j = 0; j < 32; j++) {
        float4 xv = xv4[j];
#pragma unroll
        for (int i = 0; i < 8; i++) {
            float4 w = ((const float4*)(Wq + (part * 8 + i) * 128))[j];
            o[i] += w.x * xv.x + w.y * xv.y + w.z * xv.z + w.w * xv.w;
        }
    }
    const float scale = 0.08838834764831845f;
#pragma unroll
    for (int i = 0; i < 8; i++)
        qn_g[row * 128 + part * 8 + i] = f2b(o[i] * scale);
}

// ---------------------------------------------------------------------------
// Kernel 1 (round-5 proven, ~45us): 128 rows/block, 512 threads, async
// pre-swizzled W staging via global_load_lds.
// ---------------------------------------------------------------------------
__global__ __launch_bounds__(512, 4) void k_kvproj(
    const float* __restrict__ inp, const float* __restrict__ lng,
    const float* __restrict__ lnb, const unsigned short* __restrict__ Wk_sw,
    const unsigned short* __restrict__ Wv_sw, unsigned short* __restrict__ Kbf,
    unsigned short* __restrict__ Vt)
{
    __shared__ __align__(16) unsigned short W_lds[128 * 128];  // 32 KB
    __shared__ __align__(16) unsigned short T_lds[128 * 132];  // 33.8 KB
    const int tid = threadIdx.x;
    const int wave = tid >> 6, lane = tid & 63;
    const int l15 = lane & 15, q4 = lane >> 4;
    const int kof = q4 * 8;
    const int tile0 = blockIdx.x * 128;
    const int b = tile0 >> 12;
    const int hwbase = tile0 & (HW_ - 1);

    // ---- issue Wk -> LDS async ----
    {
        const char* gw = (const char*)Wk_sw + wave * 4096 + lane * 16;
        char* lw = (char*)W_lds + wave * 4096;
#pragma unroll
        for (int j = 0; j < 4; j++)
            gload_lds16(gw + j * 1024, lw + j * 1024);
    }

    // ---- in-register LN ----
    float x[4][8];
    {
        const float* rowp = inp + (tile0 + (wave << 4) + l15) * C_;
        float s = 0.f, ss = 0.f;
#pragma unroll
        for (int ks = 0; ks < 4; ks++) {
#pragma unroll
            for (int h = 0; h < 2; h++) {
                float4 v = *(const float4*)(rowp + ks * 32 + kof + h * 4);
                x[ks][h * 4 + 0] = v.x; x[ks][h * 4 + 1] = v.y;
                x[ks][h * 4 + 2] = v.z; x[ks][h * 4 + 3] = v.w;
                s += v.x + v.y + v.z + v.w;
                ss += v.x * v.x + v.y * v.y + v.z * v.z + v.w * v.w;
            }
        }
        s += __shfl_xor(s, 16);  s += __shfl_xor(s, 32);
        ss += __shfl_xor(ss, 16); ss += __shfl_xor(ss, 32);
        float mean = s * (1.f / 128.f);
        float var = ss * (1.f / 128.f) - mean * mean;
        float rstd = rsqrtf(var + EPS_LN);
#pragma unroll
        for (int ks = 0; ks < 4; ks++) {
#pragma unroll
            for (int h = 0; h < 2; h++) {
                float4 g = *(const float4*)(lng + ks * 32 + kof + h * 4);
                float4 bb = *(const float4*)(lnb + ks * 32 + kof + h * 4);
                x[ks][h * 4 + 0] = (x[ks][h * 4 + 0] - mean) * rstd * g.x + bb.x;
                x[ks][h * 4 + 1] = (x[ks][h * 4 + 1] - mean) * rstd * g.y + bb.y;
                x[ks][h * 4 + 2] = (x[ks][h * 4 + 2] - mean) * rstd * g.z + bb.z;
                x[ks][h * 4 + 3] = (x[ks][h * 4 + 3] - mean) * rstd * g.w + bb.w;
            }
        }
    }
    short8 af[4];
#pragma unroll
    for (int ks = 0; ks < 4; ks++) {
        union { short8 s8; unsigned u[4]; } p;
#pragma unroll
        for (int j = 0; j < 4; j++)
            p.u[j] = (unsigned)f2b(x[ks][2 * j]) | ((unsigned)f2b(x[ks][2 * j + 1]) << 16);
        af[ks] = p.s8;
    }

    __syncthreads();   // [1] Wk in LDS

    // ---- K phase ----
    f32x4 acc[8];
#pragma unroll
    for (int nt = 0; nt < 8; nt++) {
        acc[nt] = (f32x4){0.f, 0.f, 0.f, 0.f};
#pragma unroll
        for (int ks = 0; ks < 4; ks++) {
            short8 bf = *(const short8*)&W_lds[(nt * 16 + l15) * 128 + ((ks * 4 + q4) ^ (l15 & 7)) * 8];
            acc[nt] = __builtin_amdgcn_mfma_f32_16x16x32_bf16(af[ks], bf, acc[nt], 0, 0, 0);
        }
    }
#pragma unroll
    for (int nt = 0; nt < 8; nt++) {
        int c = nt * 16 + l15;
#pragma unroll
        for (int i = 0; i < 4; i++)
            T_lds[((wave << 4) + (q4 << 2) + i) * 132 + c] = f2b(acc[nt][i]);
    }
    __syncthreads();   // [2]

    {
        int row = tid >> 2, part = tid & 3;
        uint4* dst = (uint4*)&Kbf[(b * HW_ + hwbase + row) * C_ + part * 32];
#pragma unroll
        for (int j = 0; j < 4; j++)
            dst[j] = *(const uint4*)&T_lds[row * 132 + part * 32 + j * 8];
    }
    // ---- issue Wv -> LDS async ----
    {
        const char* gw = (const char*)Wv_sw + wave * 4096 + lane * 16;
        char* lw = (char*)W_lds + wave * 4096;
#pragma unroll
        for (int j = 0; j < 4; j++)
            gload_lds16(gw + j * 1024, lw + j * 1024);
    }
    __syncthreads();   // [3]

    // ---- V phase ----
#pragma unroll
    for (int nt = 0; nt < 8; nt++) {
        acc[nt] = (f32x4){0.f, 0.f, 0.f, 0.f};
#pragma unroll
        for (int ks = 0; ks < 4; ks++) {
            short8 bf = *(const short8*)&W_lds[(nt * 16 + l15) * 128 + ((ks * 4 + q4) ^ (l15 & 7)) * 8];
            acc[nt] = __builtin_amdgcn_mfma_f32_16x16x32_bf16(af[ks], bf, acc[nt], 0, 0, 0);
        }
    }
#pragma unroll
    for (int nt = 0; nt < 8; nt++) {
        int c = nt * 16 + l15;
#pragma unroll
        for (int i = 0; i < 4; i++)
            T_lds[c * 132 + (wave << 4) + (q4 << 2) + i] = f2b(acc[nt][i]);
    }
    __syncthreads();   // [4]

    {
        int c = tid >> 2, part = tid & 3;
        uint4* dst = (uint4*)&Vt[(b * C_ + c) * HW_ + hwbase + part * 32];
#pragma unroll
        for (int j = 0; j < 4; j++)
            dst[j] = *(const uint4*)&T_lds[c * 132 + part * 32 + j * 8];
    }
}

// ---------------------------------------------------------------------------
// Kernel 2 v3 (per iter): 256-thread blocks (4 waves), grid (32, B).
// r6 post-mortem: Ul[4][16*132] (33.8KB) existed only to transpose/reduce the
// 4 waves' PV partials -> capped occupancy at 4 blocks/CU and cost an LDS
// round-trip + barrier. v3: each wave computes PV for a 32-channel c-slice
// over ALL 128 hw of the chunk, reading all 4 waves' P from Pb (5.1KB), and
// stores its finished slice directly to Upart. LDS 39->5.4KB => 8 blocks/CU.
// Same MFMA count, same global traffic, one barrier fewer.
// ---------------------------------------------------------------------------
__global__ __launch_bounds__(256) void k_attn(
    const unsigned short* __restrict__ qn_g, const unsigned short* __restrict__ Kbf,
    const unsigned short* __restrict__ Vt, float* __restrict__ Upart,
    float* __restrict__ rspart, float* __restrict__ a0_out, int last)
{
    __shared__ __align__(16) unsigned short Pb[4][16 * 40];  // 5.1 KB
    __shared__ float rsw[4][16];
    const int b = blockIdx.y, chunk = blockIdx.x;
    const int tid = threadIdx.x;
    const int wave = tid >> 6, lane = tid & 63;
    const int l15 = lane & 15, q4 = lane >> 4;
    const int kof = q4 * 8;
    const int hwb = chunk * 128 + wave * 32;   // this wave's score hw window
    const int cbase = wave * 32;               // this wave's PV c-slice

    short8 aq[4];
#pragma unroll
    for (int ks = 0; ks < 4; ks++)
        aq[ks] = *(const short8*)&qn_g[(b * 16 + l15) * 128 + ks * 32 + kof];
    // preload V fragments: c-slice [cbase, cbase+32), all 128 hw of the chunk
    short8 av[2][4];
#pragma unroll
    for (int ct = 0; ct < 2; ct++) {
#pragma unroll
        for (int kc = 0; kc < 4; kc++)
            av[ct][kc] = *(const short8*)&Vt[(b * C_ + cbase + ct * 16 + l15) * HW_
                                             + chunk * 128 + kc * 32 + kof];
    }

    unsigned short* Pw = &Pb[wave][0];
    float rs[4] = {0.f, 0.f, 0.f, 0.f};
#pragma unroll
    for (int s = 0; s < 2; s++) {
        int hwt = hwb + s * 16;
        f32x4 sa = {0.f, 0.f, 0.f, 0.f};
#pragma unroll
        for (int ks = 0; ks < 4; ks++) {
            short8 bk = *(const short8*)&Kbf[(b * HW_ + hwt + l15) * C_ + ks * 32 + kof];
            sa = __builtin_amdgcn_mfma_f32_16x16x32_bf16(aq[ks], bk, sa, 0, 0, 0);
        }
        float mx = fmaxf(fmaxf(sa[0], sa[1]), fmaxf(sa[2], sa[3]));
        mx = fmaxf(mx, __shfl_xor(mx, 16));
        mx = fmaxf(mx, __shfl_xor(mx, 32));
        float e[4]; float ssum = 0.f;
#pragma unroll
        for (int i = 0; i < 4; i++) { e[i] = __expf(sa[i] - mx); ssum += e[i]; }
        ssum += __shfl_xor(ssum, 16);
        ssum += __shfl_xor(ssum, 32);
        float inv = 1.f / ssum;
#pragma unroll
        for (int i = 0; i < 4; i++) {
            float a0v = e[i] * inv;
            rs[i] += a0v;
            if (last) a0_out[(b * 16 + q4 * 4 + i) * HW_ + hwt + l15] = a0v;
            Pw[(q4 * 4 + i) * 40 + s * 16 + l15] = f2b(a0v);
        }
    }
    // rowsum (this wave's 32 hw)
#pragma unroll
    for (int i = 0; i < 4; i++) {
        rs[i] += __shfl_xor(rs[i], 1);
        rs[i] += __shfl_xor(rs[i], 2);
        rs[i] += __shfl_xor(rs[i], 4);
        rs[i] += __shfl_xor(rs[i], 8);
    }
    if (l15 == 0) {
#pragma unroll
        for (int i = 0; i < 4; i++) rsw[wave][q4 * 4 + i] = rs[i];
    }
    __syncthreads();   // all waves' P visible

    // PV: accumulate over all 4 k-chunks (4 waves' P), finish c-slice
    f32x4 ua0 = {0.f, 0.f, 0.f, 0.f}, ua1 = {0.f, 0.f, 0.f, 0.f};
#pragma unroll
    for (int kc = 0; kc < 4; kc++) {
        short8 bp = *(const short8*)&Pb[kc][l15 * 40 + kof];
        ua0 = __builtin_amdgcn_mfma_f32_16x16x32_bf16(av[0][kc], bp, ua0, 0, 0, 0);
        ua1 = __builtin_amdgcn_mfma_f32_16x16x32_bf16(av[1][kc], bp, ua1, 0, 0, 0);
    }
    // direct Upart store: lane holds q = l15, c = cbase + ct*16 + q4*4 + i
    {
        float* up = Upart + (b * 32 + chunk) * 2048;
        *(f32x4*)&up[l15 * 128 + cbase + (q4 << 2)] = ua0;
        *(f32x4*)&up[l15 * 128 + cbase + 16 + (q4 << 2)] = ua1;
        if (tid < 16)
            rspart[(b * 32 + chunk) * 16 + tid] =
                rsw[0][tid] + rsw[1][tid] + rsw[2][tid] + rsw[3][tid];
    }
}

// ---------------------------------------------------------------------------
// Kernel 3 v5 (per iter): TWO rows per block, 512 threads, grid 256.
// ---------------------------------------------------------------------------
__global__ __launch_bounds__(512) void k_tail(
    const float* __restrict__ Upart, const float* __restrict__ rspart,
    const float* __restrict__ hsrc, float* __restrict__ q_buf,
    const unsigned short* __restrict__ wihT, const unsigned short* __restrict__ whhT,
    const float* __restrict__ bih, const float* __restrict__ bhh,
    const float* __restrict__ ln2g, const float* __restrict__ ln2b,
    const unsigned short* __restrict__ w1T, const float* __restrict__ b1,
    const unsigned short* __restrict__ w2T, const float* __restrict__ b2,
    const float* __restrict__ lnqg, const float* __restrict__ lnqb,
    const float* __restrict__ wqTf, unsigned short* __restrict__ qn_g,
    float* __restrict__ out_q, int last)
{
    __shared__ __align__(16) float red0[512], red1[512];
    __shared__ __align__(16) float u0_l[128], u1_l[128];
    __shared__ __align__(16) float h0_l[128], h1_l[128];
    __shared__ __align__(16) float y0_l[128], y1_l[128];
    __shared__ __align__(16) float z0_l[128], z1_l[128];
    __shared__ __align__(16) float g0_l[768], g1_l[768];
    __shared__ __align__(16) float f0_l[512], f1_l[512];
    __shared__ float srs0, srs1;
    const int tid = threadIdx.x;
    const int row0 = blockIdx.x * 2, row1 = row0 + 1;
    const int b = row0 >> 4, q0 = row0 & 15;

    // ---- Phase 0: Upart partial reduce (both rows); h loads; rspart ----
    {
        int c = tid & 127, h = tid >> 7;   // h in 0..3, 8 chunks each
        const float* upA = Upart + (b * 32 + h * 8) * 2048 + q0 * 128 + c;
        float a = 0.f, bv = 0.f;
#pragma unroll
        for (int ch = 0; ch < 8; ch++) {
            a  += upA[ch * 2048];
            bv += upA[ch * 2048 + 128];    // q1 = q0+1
        }
        red0[tid] = a; red1[tid] = bv;
        if (tid < 128) h0_l[tid] = hsrc[row0 * 128 + tid];
        else if (tid < 256) h1_l[tid - 128] = hsrc[row1 * 128 + (tid - 128)];
        if (tid >= 256 && tid < 288) {
            int t = tid - 256;
            float v = rspart[(b * 32 + t) * 16 + q0];
            v += __shfl_xor(v, 1); v += __shfl_xor(v, 2); v += __shfl_xor(v, 4);
            v += __shfl_xor(v, 8); v += __shfl_xor(v, 16);
            if (t == 0) srs0 = v;
        }
        if (tid >= 320 && tid < 352) {
            int t = tid - 320;
            float v = rspart[(b * 32 + t) * 16 + q0 + 1];
            v += __shfl_xor(v, 1); v += __shfl_xor(v, 2); v += __shfl_xor(v, 4);
            v += __shfl_xor(v, 8); v += __shfl_xor(v, 16);
            if (t == 0) srs1 = v;
        }
    }
    __syncthreads();
    if (tid < 128) {
        float s = red0[tid] + red0[tid + 128] + red0[tid + 256] + red0[tid + 384];
        u0_l[tid] = s / (srs0 + EPS_ATTN);
    } else if (tid < 256) {
        int c = tid - 128;
        float s = red1[c] + red1[c + 128] + red1[c + 256] + red1[c + 384];
        u1_l[c] = s / (srs1 + EPS_ATTN);
    }
    __syncthreads();
    // ---- GRU gates: 768 outputs x 2 rows; weight loaded once per output ----
    {
        int o = tid;
        const uint2* wp; const float *sA, *sB; float bias;
        if (o < 384) { wp = (const uint2*)wihT + o; sA = u0_l; sB = u1_l; bias = bih[o]; }
        else         { wp = (const uint2*)whhT + (o - 384); sA = h0_l; sB = h1_l; bias = bhh[o - 384]; }
        float fa = 0.f, fb = 0.f;
#pragma unroll 4
        for (int g = 0; g < 32; g++) {
            uint2 w = wp[g * 384];
            float4 a4 = *(const float4*)&sA[g * 4];
            float4 b4 = *(const float4*)&sB[g * 4];
            float w0 = blo(w.x), w1v = bhi(w.x), w2v = blo(w.y), w3 = bhi(w.y);
            fa += w0 * a4.x + w1v * a4.y + w2v * a4.z + w3 * a4.w;
            fb += w0 * b4.x + w1v * b4.y + w2v * b4.z + w3 * b4.w;
        }
        g0_l[o] = fa + bias; g1_l[o] = fb + bias;
        if (tid < 256) {
            int o2 = tid + 512;            // 512..767 -> whh rows 128..383
            const uint2* wp2 = (const uint2*)whhT + (o2 - 384);
            float fa2 = 0.f, fb2 = 0.f;
#pragma unroll 4
            for (int g = 0; g < 32; g++) {
                uint2 w = wp2[g * 384];
                float4 a4 = *(const float4*)&h0_l[g * 4];
                float4 b4 = *(const float4*)&h1_l[g * 4];
                float w0 = blo(w.x), w1v = bhi(w.x), w2v = blo(w.y), w3 = bhi(w.y);
                fa2 += w0 * a4.x + w1v * a4.y + w2v * a4.z + w3 * a4.w;
                fb2 += w0 * b4.x + w1v * b4.y + w2v * b4.z + w3 * b4.w;
            }
            float bias2 = bhh[o2 - 384];
            g0_l[o2] = fa2 + bias2; g1_l[o2] = fb2 + bias2;
        }
    }
    __syncthreads();
    // ---- GRU elementwise: 2 rows x 128 channels ----
    if (tid < 256) {
        int c = tid & 127, r = tid >> 7;
        const float* gl = r ? g1_l : g0_l;
        const float* hl = r ? h1_l : h0_l;
        float* yl = r ? y1_l : y0_l;
        float ir = gl[c], iz = gl[128 + c], in_ = gl[256 + c];
        float hr = gl[384 + c], hz = gl[512 + c], hn = gl[640 + c];
        float rr = 1.f / (1.f + expf(-(ir + hr)));
        float zz = 1.f / (1.f + expf(-(iz + hz)));
        float nn = tanhf(in_ + rr * hn);
        yl[c] = (1.f - zz) * nn + zz * hl[c];
    }
    __syncthreads();
    // ---- LN2: waves 0-3 handle row0, waves 4-7 row1 (redundant stats) ----
    {
        int r = tid >> 8;
        const float* yl = r ? y1_l : y0_l;
        int l = tid & 63;
        float v0 = yl[l], v1 = yl[l + 64];
        float s = v0 + v1, ss = v0 * v0 + v1 * v1;
#pragma unroll
        for (int off = 1; off < 64; off <<= 1) {
            s += __shfl_xor(s, off);
            ss += __shfl_xor(ss, off);
        }
        float mean = s * (1.f / 128.f);
        float var = ss * (1.f / 128.f) - mean * mean;
        float rstd = rsqrtf(var + EPS_LN);
        int c = tid & 255;
        if (c < 128) {
            float* zl = r ? z1_l : z0_l;
            zl[c] = (yl[c] - mean) * rstd * ln2g[c] + ln2b[c];
        }
    }
    __syncthreads();
    // ---- FFN1: 512 outputs, full K dot, both rows per weight load ----
    {
        const uint2* wp = (const uint2*)w1T + tid;
        float fa = 0.f, fb = 0.f;
#pragma unroll 4
        for (int g = 0; g < 32; g++) {
            uint2 w = wp[g * 512];
            float4 za = *(const float4*)&z0_l[g * 4];
            float4 zb = *(const float4*)&z1_l[g * 4];
            float w0 = blo(w.x), w1v = bhi(w.x), w2v = blo(w.y), w3 = bhi(w.y);
            fa += w0 * za.x + w1v * za.y + w2v * za.z + w3 * za.w;
            fb += w0 * zb.x + w1v * zb.y + w2v * zb.z + w3 * zb.w;
        }
        float bb = b1[tid];
        f0_l[tid] = fmaxf(fa + bb, 0.f);
        f1_l[tid] = fmaxf(fb + bb, 0.f);
    }
    __syncthreads();
    // ---- FFN2: 128 outputs x 4 K-groups, both rows ----
    {
        int c = tid & 127, k4 = tid >> 7;
        const uint2* wp = (const uint2*)w2T + c;
        float fa = 0.f, fb = 0.f;
#pragma unroll 4
        for (int j = 0; j < 32; j++) {
            int g = k4 * 32 + j;
            uint2 w = wp[g * 128];
            float4 ha = *(const float4*)&f0_l[g * 4];
            float4 hb = *(const float4*)&f1_l[g * 4];
            float w0 = blo(w.x), w1v = bhi(w.x), w2v = blo(w.y), w3 = bhi(w.y);
            fa += w0 * ha.x + w1v * ha.y + w2v * ha.z + w3 * ha.w;
            fb += w0 * hb.x + w1v * hb.y + w2v * hb.z + w3 * hb.w;
        }
        red0[tid] = fa; red1[tid] = fb;
    }
    __syncthreads();
    if (tid < 128) {
        float f2 = red0[tid] + red0[tid + 128] + red0[tid + 256] + red0[tid + 384];
        float qn = y0_l[tid] + f2 + b2[tid];
        u0_l[tid] = qn;
        q_buf[row0 * 128 + tid] = qn;
        if (last) out_q[row0 * 128 + tid] = qn;
    } else if (tid < 256) {
        int c = tid - 128;
        float f2 = red1[c] + red1[c + 128] + red1[c + 256] + red1[c + 384];
        float qn = y1_l[c] + f2 + b2[c];
        u1_l[c] = qn;
        q_buf[row1 * 128 + c] = qn;
        if (last) out_q[row1 * 128 + c] = qn;
    }
    if (last) return;
    __syncthreads();
    // ---- LN(q_new): dual-row redundant stats ----
    {
        int r = tid >> 8;
        const float* yl = r ? u1_l : u0_l;
        int l = tid & 63;
        float v0 = yl[l], v1 = yl[l + 64];
        float s = v0 + v1, ss = v0 * v0 + v1 * v1;
#pragma unroll
        for (int off = 1; off < 64; off <<= 1) {
            s += __shfl_xor(s, off);
            ss += __shfl_xor(ss, off);
        }
        float mean = s * (1.f / 128.f);
        float var = ss * (1.f / 128.f) - mean * mean;
        float rstd = rsqrtf(var + EPS_LN);
        int c = tid & 255;
        if (c < 128) {
            float* zl = r ? z1_l : z0_l;
            zl[c] = (yl[c] - mean) * rstd * lnqg[c] + lnqb[c];
        }
    }
    __syncthreads();
    // ---- qn_next = LN(q_new) @ Wq^T * scale (fp32 packed, both rows) ----
    {
        int c = tid & 127, k4 = tid >> 7;
        const float4* wp = (const float4*)wqTf + c;
        float fa = 0.f, fb = 0.f;
#pragma unroll
        for (int j = 0; j < 8; j++) {
            int g = k4 * 8 + j;
            float4 w = wp[g * 128];
            float4 za = *(const float4*)&z0_l[g * 4];
            float4 zb = *(const float4*)&z1_l[g * 4];
            fa += w.x * za.x + w.y * za.y + w.z * za.z + w.w * za.w;
            fb += w.x * zb.x + w.y * zb.y + w.z * zb.z + w.w * zb.w;
        }
        red0[tid] = fa; red1[tid] = fb;
    }
    __syncthreads();
    if (tid < 128) {
        float qa = red0[tid] + red0[tid + 128] + red0[tid + 256] + red0[tid + 384];
        qn_g[row0 * 128 + tid] = f2b(qa * 0.08838834764831845f);
    } else if (tid < 256) {
        int c = tid - 128;
        float qa = red1[c] + red1[c + 128] + red1[c + 256] + red1[c + 384];
        qn_g[row1 * 128 + c] = f2b(qa * 0.08838834764831845f);
    }
}

// ---------------------------------------------------------------------------
extern "C" void kernel_launch(void* const* d_in, const int* in_sizes, int n_in,
                              void* d_out, int out_size, void* d_ws, size_t ws_size,
                              hipStream_t stream) {
    const float* inp     = (const float*)d_in[0];
    const float* query   = (const float*)d_in[1];
    const float* ln_kv_g = (const float*)d_in[2];
    const float* ln_kv_b = (const float*)d_in[3];
    const float* Wk      = (const float*)d_in[4];
    const float* Wv      = (const float*)d_in[5];
    const float* ln_q_g  = (const float*)d_in[6];
    const float* ln_q_b  = (const float*)d_in[7];
    const float* Wq      = (const float*)d_in[8];
    const float* gru_wih = (const float*)d_in[9];
    const float* gru_whh = (const float*)d_in[10];
    const float* gru_bih = (const float*)d_in[11];
    const float* gru_bhh = (const float*)d_in[12];
    const float* ln2_g   = (const float*)d_in[13];
    const float* ln2_b   = (const float*)d_in[14];
    const float* ffn_w1  = (const float*)d_in[15];
    const float* ffn_b1  = (const float*)d_in[16];
    const float* ffn_w2  = (const float*)d_in[17];
    const float* ffn_b2  = (const float*)d_in[18];

    char* ws = (char*)d_ws;
    unsigned short* Kbf    = (unsigned short*)ws;                  // 33554432
    unsigned short* Vt     = (unsigned short*)(ws + 33554432);     // 33554432
    float* q_buf           = (float*)(ws + 67108864);              // 262144
    float* Upart           = (float*)(ws + 67371008);              // 8388608
    float* rspart          = (float*)(ws + 75759616);              // 65536
    unsigned short* qn_g   = (unsigned short*)(ws + 75825152);     // 131072
    unsigned short* Wk_sw  = (unsigned short*)(ws + 75956224);     // 32768
    unsigned short* Wv_sw  = (unsigned short*)(ws + 75988992);     // 32768
    unsigned short* wihT   = (unsigned short*)(ws + 76021760);     // 98304
    unsigned short* whhT   = (unsigned short*)(ws + 76120064);     // 98304
    unsigned short* w1T    = (unsigned short*)(ws + 76218368);     // 131072
    unsigned short* w2T    = (unsigned short*)(ws + 76349440);     // 131072
    float* wqTf            = (float*)(ws + 76480512);              // 65536

    float* out_q  = (float*)d_out;
    float* out_a0 = out_q + B_ * N_ * C_;

    k_prep<<<dim3(304), dim3(256), 0, stream>>>(
        Wk, Wv, gru_wih, gru_whh, ffn_w1, ffn_w2,
        Wk_sw, Wv_sw, wihT, whhT, w1T, w2T,
        query, ln_q_g, ln_q_b, Wq, wqTf, qn_g);
    k_kvproj<<<dim3((B_ * HW_) / 128), dim3(512), 0, stream>>>(
        inp, ln_kv_g, ln_kv_b, Wk_sw, Wv_sw, Kbf, Vt);

    for (int it = 0; it < ITERS_; it++) {
        int last = (it == ITERS_ - 1) ? 1 : 0;
        const float* hsrc = (it == 0) ? query : q_buf;
        k_attn<<<dim3(32, B_), dim3(256), 0, stream>>>(
            qn_g, Kbf, Vt, Upart, rspart, out_a0, last);
        k_tail<<<dim3((B_ * N_) / 2), dim3(512), 0, stream>>>(
            Upart, rspart, hsrc, q_buf, wihT, whhT, gru_bih, gru_bhh,
            ln2_g, ln2_b, w1T, ffn_b1, w2T, ffn_b2,
            ln_q_g, ln_q_b, wqTf, qn_g, out_q, last);
    }
}